// Round 3
// baseline (142.392 us; speedup 1.0000x reference)
//
#include <hip/hip_runtime.h>
#include <hip/hip_cooperative_groups.h>
#include <math.h>

namespace cg = cooperative_groups;

#define TWO_PI_F 6.2831853071795864769f

// Branchless erf-based exact GELU (A&S 7.1.26, |err|<=1.5e-7).
__device__ __forceinline__ float gelu_f(float v) {
    const float y  = v * 0.70710678118654752f;
    const float ay = fabsf(y);
    const float t  = __builtin_amdgcn_rcpf(fmaf(0.3275911f, ay, 1.0f));
    const float e  = __builtin_amdgcn_exp2f(-1.4426950408889634f * y * y);
    float p = fmaf(1.061405429f, t, -1.453152027f);
    p = fmaf(p, t, 1.421413741f);
    p = fmaf(p, t, -0.284496736f);
    p = fmaf(p, t, 0.254829592f);
    const float erf_abs = 1.0f - p * t * e;
    const float erf_v   = copysignf(erf_abs, v);
    const float hv = 0.5f * v;
    return fmaf(hv, erf_v, hv);
}

// per-row tail using folded internal path: h_r2 = (I + M4)@h_r + cvec
__device__ __forceinline__ void row_tail_m4(
    const float xr[4],
    const float* __restrict__ rw, const float* __restrict__ rb,
    const float* __restrict__ tfp,
    const float m4[16], const float cvec[4],
    const float* __restrict__ wo1, const float* __restrict__ bo1,
    const float* __restrict__ wo2, const float* __restrict__ bo2,
    float c0, float c1, float sr, float o[4])
{
    float t[4];
#pragma unroll
    for (int j = 0; j < 4; ++j) {
        float l0 = 0.f, l1 = 0.f, bse = rb[j];
#pragma unroll
        for (int k = 0; k < 4; ++k) {
            l0  = fmaf(tfp[j*4+k],      xr[k], l0);
            l1  = fmaf(tfp[16 + j*4+k], xr[k], l1);
            bse = fmaf(rw[j*4+k],       xr[k], bse);
        }
        const float corr = __sinf(c0 * l0) * l0 + 0.5f * __sinf(c1 * l1) * l1;
        t[j] = fmaf(sr, corr, bse);
    }
    const float mu = 0.25f * (t[0] + t[1] + t[2] + t[3]);
    float d0 = t[0]-mu, d1 = t[1]-mu, d2 = t[2]-mu, d3 = t[3]-mu;
    const float var = 0.25f * (d0*d0 + d1*d1 + d2*d2 + d3*d3);
    const float inv = rsqrtf(var + 1e-5f);
    float hr[4] = { gelu_f(d0*inv), gelu_f(d1*inv), gelu_f(d2*inv), gelu_f(d3*inv) };

    float h2[4];
#pragma unroll
    for (int l = 0; l < 4; ++l) {
        float a = hr[l] + cvec[l];
#pragma unroll
        for (int j = 0; j < 4; ++j) a = fmaf(m4[l*4+j], hr[j], a);
        h2[l] = a;
    }
    float hid[8];
#pragma unroll
    for (int h = 0; h < 8; ++h) {
        float a = bo1[h];
#pragma unroll
        for (int l = 0; l < 4; ++l) a = fmaf(wo1[h*4+l], h2[l], a);
        hid[h] = gelu_f(a);
    }
#pragma unroll
    for (int oo = 0; oo < 4; ++oo) {
        float a = bo2[oo];
#pragma unroll
        for (int h = 0; h < 8; ++h) a = fmaf(wo2[oo*8+h], hid[h], a);
        o[oo] = a;
    }
}

// =================== cooperative fused kernel: single pass over x ===================
// 256 thr/block, 4 row-pairs (8 rows) per thread held in registers across grid.sync.
__global__ __launch_bounds__(256, 4) void k_fused(
    const float* __restrict__ x,
    const float* __restrict__ W_in, const float* __restrict__ b_in,
    const float* __restrict__ r_w,  const float* __restrict__ r_b,
    const float* __restrict__ r_tf, const float* __restrict__ r_tc,
    const float* __restrict__ i_w,  const float* __restrict__ i_b,
    const float* __restrict__ i_tf, const float* __restrict__ i_tc,
    const float* __restrict__ W_ri, const float* __restrict__ b_ri,
    const float* __restrict__ W_ir, const float* __restrict__ b_ir,
    const float* __restrict__ flow_gate, const float* __restrict__ mem,
    const float* __restrict__ W_o1, const float* __restrict__ b_o1,
    const float* __restrict__ W_o2, const float* __restrict__ b_o2,
    float* __restrict__ partials, float* __restrict__ out, int B)
{
    const int tid  = threadIdx.x;
    const int bid  = blockIdx.x;
    const int TT   = gridDim.x * 256;
    const int gtid = bid * 256 + tid;

    __shared__ float s_hc[16], s_cv4[4], s_m4[16], s_red[8], s_c[2];

    // ---- Phase A: fold internal path (weights-only; independent of batch stats) ----
    if (tid < 64) {
        const int j = tid & 15;
        float base = i_b[j];
#pragma unroll
        for (int k = 0; k < 16; ++k) base = fmaf(i_w[j*16 + k], mem[k], base);
        float corr = 0.f;
#pragma unroll
        for (int n = 0; n < 3; ++n) {
            float lo = 0.f;
#pragma unroll
            for (int k = 0; k < 16; ++k) lo = fmaf(i_tf[n*256 + j*16 + k], mem[k], lo);
            float a = fabsf(lo);
            a += __shfl_xor(a, 1); a += __shfl_xor(a, 2); a += __shfl_xor(a, 4); a += __shfl_xor(a, 8);
            const float mean = a * (1.0f/16.0f);
            const float phase = TWO_PI_F * (float)(n+1) * lo / (mean + 1e-8f);
            corr = fmaf(sinf(phase), lo / (float)(n+1), corr);
        }
        const float sc = 1.0f / (1.0f + expf(-i_tc[0]));
        const float t = fmaf(sc, corr, base);
        float mu = t;
        mu += __shfl_xor(mu, 1); mu += __shfl_xor(mu, 2); mu += __shfl_xor(mu, 4); mu += __shfl_xor(mu, 8);
        mu *= (1.0f/16.0f);
        const float d = t - mu;
        float v = d*d;
        v += __shfl_xor(v, 1); v += __shfl_xor(v, 2); v += __shfl_xor(v, 4); v += __shfl_xor(v, 8);
        v *= (1.0f/16.0f);
        const float h = gelu_f(d * rsqrtf(v + 1e-5f));
        if (tid < 16) s_hc[j] = h;
    }
    __syncthreads();
    const float g = 1.0f / (1.0f + expf(-flow_gate[0]));
    if (tid < 4) {
        float acc = 0.f;
#pragma unroll
        for (int m = 0; m < 16; ++m) acc = fmaf(W_ir[tid*16 + m], fmaf(g, b_ri[m], s_hc[m]), acc);
        s_cv4[tid] = g * (acc + b_ir[tid]);
    }
    if (tid < 16) {
        const int l = tid >> 2, j = tid & 3;
        float M = 0.f;
#pragma unroll
        for (int m = 0; m < 16; ++m) M = fmaf(W_ir[l*16 + m], W_ri[m*4 + j], M);
        s_m4[tid] = g * g * M;
    }
    // consumed after later __syncthreads (phase C)

    // ---- Phase B: xr = gelu(x@W_in+b) kept in regs; accumulate |lo_n| sums ----
    const int npairs = B >> 1;
    float s0 = 0.f, s1 = 0.f;
    float xr[4][2][4];
    float xrt[4];
#pragma unroll
    for (int c = 0; c < 4; ++c) {
        const int p = c * TT + gtid;
        if (p < npairs) {
            const float4* xp = (const float4*)(x + (size_t)p * 12);
            float4 q0 = xp[0], q1 = xp[1], q2 = xp[2];
            float xv[2][6] = {{q0.x, q0.y, q0.z, q0.w, q1.x, q1.y},
                              {q1.z, q1.w, q2.x, q2.y, q2.z, q2.w}};
#pragma unroll
            for (int r = 0; r < 2; ++r) {
#pragma unroll
                for (int j = 0; j < 4; ++j) {
                    float a = b_in[j];
#pragma unroll
                    for (int k = 0; k < 6; ++k) a = fmaf(W_in[j*6+k], xv[r][k], a);
                    xr[c][r][j] = gelu_f(a);
                }
#pragma unroll
                for (int j = 0; j < 4; ++j) {
                    float l0 = 0.f, l1 = 0.f;
#pragma unroll
                    for (int k = 0; k < 4; ++k) {
                        l0 = fmaf(r_tf[j*4+k],      xr[c][r][k], l0);
                        l1 = fmaf(r_tf[16 + j*4+k], xr[c][r][k], l1);
                    }
                    s0 += fabsf(l0);
                    s1 += fabsf(l1);
                }
            }
        }
    }
    if ((B & 1) && gtid == 0) {
        const float* xs = x + (size_t)(B - 1) * 6;
        float xv[6];
#pragma unroll
        for (int k = 0; k < 6; ++k) xv[k] = xs[k];
#pragma unroll
        for (int j = 0; j < 4; ++j) {
            float a = b_in[j];
#pragma unroll
            for (int k = 0; k < 6; ++k) a = fmaf(W_in[j*6+k], xv[k], a);
            xrt[j] = gelu_f(a);
        }
#pragma unroll
        for (int j = 0; j < 4; ++j) {
            float l0 = 0.f, l1 = 0.f;
#pragma unroll
            for (int k = 0; k < 4; ++k) {
                l0 = fmaf(r_tf[j*4+k],      xrt[k], l0);
                l1 = fmaf(r_tf[16 + j*4+k], xrt[k], l1);
            }
            s0 += fabsf(l0);
            s1 += fabsf(l1);
        }
    }

#pragma unroll
    for (int off = 32; off > 0; off >>= 1) {
        s0 += __shfl_down(s0, off);
        s1 += __shfl_down(s1, off);
    }
    if ((tid & 63) == 0) { s_red[(tid>>6)*2] = s0; s_red[(tid>>6)*2+1] = s1; }
    __syncthreads();
    if (tid == 0) {
        partials[(size_t)bid*2]     = s_red[0] + s_red[2] + s_red[4] + s_red[6];
        partials[(size_t)bid*2 + 1] = s_red[1] + s_red[3] + s_red[5] + s_red[7];
    }

    cg::this_grid().sync();

    // ---- Phase C: every block reduces the grid partials (deterministic order) ----
    float t0 = 0.f, t1 = 0.f;
    for (int k = tid; k < (int)gridDim.x; k += 256) {
        t0 += partials[(size_t)k*2];
        t1 += partials[(size_t)k*2 + 1];
    }
#pragma unroll
    for (int off = 32; off > 0; off >>= 1) {
        t0 += __shfl_down(t0, off);
        t1 += __shfl_down(t1, off);
    }
    __syncthreads();   // s_red reuse
    if ((tid & 63) == 0) { s_red[(tid>>6)*2] = t0; s_red[(tid>>6)*2+1] = t1; }
    __syncthreads();
    if (tid == 0) {
        const float u0 = s_red[0] + s_red[2] + s_red[4] + s_red[6];
        const float u1 = s_red[1] + s_red[3] + s_red[5] + s_red[7];
        const float m0 = u0 / (4.0f * (float)B);
        const float m1 = u1 / (4.0f * (float)B);
        s_c[0] = TWO_PI_F * 1.0f / (m0 + 1e-8f);
        s_c[1] = TWO_PI_F * 2.0f / (m1 + 1e-8f);
    }
    __syncthreads();
    const float c0 = s_c[0], c1 = s_c[1];
    const float sr = 1.0f / (1.0f + expf(-r_tc[0]));

    // ---- Phase D: finish rows from registers, write out ----
    float m4[16], cvec[4];
#pragma unroll
    for (int i = 0; i < 16; ++i) m4[i] = s_m4[i];
#pragma unroll
    for (int i = 0; i < 4; ++i) cvec[i] = s_cv4[i];

#pragma unroll
    for (int c = 0; c < 4; ++c) {
        const int p = c * TT + gtid;
        if (p < npairs) {
#pragma unroll
            for (int r = 0; r < 2; ++r) {
                float o[4];
                row_tail_m4(xr[c][r], r_w, r_b, r_tf, m4, cvec,
                            W_o1, b_o1, W_o2, b_o2, c0, c1, sr, o);
                ((float4*)out)[(size_t)2*p + r] = make_float4(o[0], o[1], o[2], o[3]);
            }
        }
    }
    if ((B & 1) && gtid == 0) {
        float o[4];
        row_tail_m4(xrt, r_w, r_b, r_tf, m4, cvec,
                    W_o1, b_o1, W_o2, b_o2, c0, c1, sr, o);
        ((float4*)out)[(size_t)B - 1] = make_float4(o[0], o[1], o[2], o[3]);
    }
}

// =================== fallback path (non-cooperative, 3 kernels) ===================
__global__ __launch_bounds__(256) void k_pass1(
    const float* __restrict__ x,
    const float* __restrict__ W_in, const float* __restrict__ b_in,
    const float* __restrict__ r_tf,
    float* __restrict__ partials, int B)
{
    float s0 = 0.f, s1 = 0.f;
    const int np = B >> 1;
    const int stride = gridDim.x * blockDim.x;
    for (int p = blockIdx.x * blockDim.x + threadIdx.x; p < np; p += stride) {
        const float4* xp = (const float4*)(x + (size_t)p * 12);
        float4 q0 = xp[0], q1 = xp[1], q2 = xp[2];
        float xv[2][6] = {{q0.x, q0.y, q0.z, q0.w, q1.x, q1.y},
                          {q1.z, q1.w, q2.x, q2.y, q2.z, q2.w}};
#pragma unroll
        for (int r = 0; r < 2; ++r) {
            float xr[4];
#pragma unroll
            for (int j = 0; j < 4; ++j) {
                float a = b_in[j];
#pragma unroll
                for (int k = 0; k < 6; ++k) a = fmaf(W_in[j*6+k], xv[r][k], a);
                xr[j] = gelu_f(a);
            }
#pragma unroll
            for (int j = 0; j < 4; ++j) {
                float l0 = 0.f, l1 = 0.f;
#pragma unroll
                for (int k = 0; k < 4; ++k) {
                    l0 = fmaf(r_tf[j*4+k],      xr[k], l0);
                    l1 = fmaf(r_tf[16 + j*4+k], xr[k], l1);
                }
                s0 += fabsf(l0);
                s1 += fabsf(l1);
            }
        }
    }
    if ((B & 1) && blockIdx.x == 0 && threadIdx.x == 0) {
        const float* xs = x + (size_t)(B-1) * 6;
        float xr[4];
#pragma unroll
        for (int j = 0; j < 4; ++j) {
            float a = b_in[j];
#pragma unroll
            for (int k = 0; k < 6; ++k) a = fmaf(W_in[j*6+k], xs[k], a);
            xr[j] = gelu_f(a);
        }
#pragma unroll
        for (int j = 0; j < 4; ++j) {
            float l0 = 0.f, l1 = 0.f;
#pragma unroll
            for (int k = 0; k < 4; ++k) {
                l0 = fmaf(r_tf[j*4+k],      xr[k], l0);
                l1 = fmaf(r_tf[16 + j*4+k], xr[k], l1);
            }
            s0 += fabsf(l0);
            s1 += fabsf(l1);
        }
    }
#pragma unroll
    for (int off = 32; off > 0; off >>= 1) {
        s0 += __shfl_down(s0, off);
        s1 += __shfl_down(s1, off);
    }
    __shared__ float sm[8];
    if ((threadIdx.x & 63) == 0) { sm[(threadIdx.x>>6)*2] = s0; sm[(threadIdx.x>>6)*2+1] = s1; }
    __syncthreads();
    if (threadIdx.x == 0) {
        partials[(size_t)blockIdx.x*2]     = sm[0]+sm[2]+sm[4]+sm[6];
        partials[(size_t)blockIdx.x*2 + 1] = sm[1]+sm[3]+sm[5]+sm[7];
    }
}

// cst layout: [0]=c0 [1]=c1 [2]=sr [8..23]=M4 [24..27]=cvec
__global__ __launch_bounds__(256) void k_mid(
    const float* __restrict__ partials, int nb, int B,
    const float* __restrict__ i_w,  const float* __restrict__ i_b,
    const float* __restrict__ i_tf, const float* __restrict__ i_tc,
    const float* __restrict__ W_ri, const float* __restrict__ b_ri,
    const float* __restrict__ W_ir, const float* __restrict__ b_ir,
    const float* __restrict__ flow_gate, const float* __restrict__ mem,
    const float* __restrict__ r_tc,
    float* __restrict__ cst)
{
    __shared__ float red[8];
    __shared__ float hc[16];

    float s0 = 0.f, s1 = 0.f;
    for (int k = threadIdx.x; k < nb; k += blockDim.x) {
        s0 += partials[(size_t)k*2];
        s1 += partials[(size_t)k*2 + 1];
    }
#pragma unroll
    for (int off = 32; off > 0; off >>= 1) { s0 += __shfl_down(s0, off); s1 += __shfl_down(s1, off); }
    if ((threadIdx.x & 63) == 0) { red[(threadIdx.x>>6)*2] = s0; red[(threadIdx.x>>6)*2+1] = s1; }
    __syncthreads();
    if (threadIdx.x == 0) {
        const float t0 = red[0]+red[2]+red[4]+red[6];
        const float t1 = red[1]+red[3]+red[5]+red[7];
        const float m0 = t0 / (4.0f * (float)B);
        const float m1 = t1 / (4.0f * (float)B);
        cst[0] = TWO_PI_F * 1.0f / (m0 + 1e-8f);
        cst[1] = TWO_PI_F * 2.0f / (m1 + 1e-8f);
        cst[2] = 1.0f / (1.0f + expf(-r_tc[0]));
    }

    if (threadIdx.x < 64) {
        const int j = threadIdx.x & 15;
        float base = i_b[j];
#pragma unroll
        for (int k = 0; k < 16; ++k) base = fmaf(i_w[j*16 + k], mem[k], base);
        float corr = 0.f;
#pragma unroll
        for (int n = 0; n < 3; ++n) {
            float lo = 0.f;
#pragma unroll
            for (int k = 0; k < 16; ++k) lo = fmaf(i_tf[n*256 + j*16 + k], mem[k], lo);
            float a = fabsf(lo);
            a += __shfl_xor(a, 1); a += __shfl_xor(a, 2); a += __shfl_xor(a, 4); a += __shfl_xor(a, 8);
            const float mean = a * (1.0f/16.0f);
            const float phase = TWO_PI_F * (float)(n+1) * lo / (mean + 1e-8f);
            corr = fmaf(sinf(phase), lo / (float)(n+1), corr);
        }
        const float sc = 1.0f / (1.0f + expf(-i_tc[0]));
        const float t = fmaf(sc, corr, base);
        float mu = t;
        mu += __shfl_xor(mu, 1); mu += __shfl_xor(mu, 2); mu += __shfl_xor(mu, 4); mu += __shfl_xor(mu, 8);
        mu *= (1.0f/16.0f);
        const float d = t - mu;
        float v = d*d;
        v += __shfl_xor(v, 1); v += __shfl_xor(v, 2); v += __shfl_xor(v, 4); v += __shfl_xor(v, 8);
        v *= (1.0f/16.0f);
        const float h = gelu_f(d * rsqrtf(v + 1e-5f));
        if (threadIdx.x < 16) hc[j] = h;
    }
    __syncthreads();

    const float g = 1.0f / (1.0f + expf(-flow_gate[0]));
    if (threadIdx.x < 4) {
        float acc = 0.f;
#pragma unroll
        for (int m = 0; m < 16; ++m) acc = fmaf(W_ir[threadIdx.x*16 + m], fmaf(g, b_ri[m], hc[m]), acc);
        cst[24 + threadIdx.x] = g * (acc + b_ir[threadIdx.x]);
    }
    if (threadIdx.x < 16) {
        const int l = threadIdx.x >> 2, j = threadIdx.x & 3;
        float M = 0.f;
#pragma unroll
        for (int m = 0; m < 16; ++m) M = fmaf(W_ir[l*16 + m], W_ri[m*4 + j], M);
        cst[8 + threadIdx.x] = g * g * M;
    }
}

__global__ __launch_bounds__(256) void k_pass2(
    const float* __restrict__ x,
    const float* __restrict__ W_in, const float* __restrict__ b_in,
    const float* __restrict__ r_w,  const float* __restrict__ r_b,
    const float* __restrict__ r_tf,
    const float* __restrict__ W_o1, const float* __restrict__ b_o1,
    const float* __restrict__ W_o2, const float* __restrict__ b_o2,
    const float* __restrict__ cst,
    float* __restrict__ out, int B)
{
    float m4[16], cvec[4];
#pragma unroll
    for (int i = 0; i < 16; ++i) m4[i] = cst[8 + i];
#pragma unroll
    for (int i = 0; i < 4; ++i)  cvec[i] = cst[24 + i];
    const float c0 = cst[0], c1 = cst[1], sr = cst[2];

    const int stride = gridDim.x * blockDim.x;
    for (int i = blockIdx.x * blockDim.x + threadIdx.x; i < B; i += stride) {
        const float2* xp = (const float2*)(x + (size_t)i * 6);
        float2 p0 = xp[0], p1 = xp[1], p2 = xp[2];
        float xv[6] = {p0.x, p0.y, p1.x, p1.y, p2.x, p2.y};
        float xr[4];
#pragma unroll
        for (int j = 0; j < 4; ++j) {
            float a = b_in[j];
#pragma unroll
            for (int k = 0; k < 6; ++k) a = fmaf(W_in[j*6+k], xv[k], a);
            xr[j] = gelu_f(a);
        }
        float o[4];
        row_tail_m4(xr, r_w, r_b, r_tf, m4, cvec, W_o1, b_o1, W_o2, b_o2, c0, c1, sr, o);
        ((float4*)out)[i] = make_float4(o[0], o[1], o[2], o[3]);
    }
}

extern "C" void kernel_launch(void* const* d_in, const int* in_sizes, int n_in,
                              void* d_out, int out_size, void* d_ws, size_t ws_size,
                              hipStream_t stream)
{
    const float* x    = (const float*)d_in[0];
    const float* W_in = (const float*)d_in[1];
    const float* b_in = (const float*)d_in[2];
    const float* r_w  = (const float*)d_in[3];
    const float* r_b  = (const float*)d_in[4];
    const float* r_tf = (const float*)d_in[5];
    const float* r_tc = (const float*)d_in[6];
    const float* i_w  = (const float*)d_in[7];
    const float* i_b  = (const float*)d_in[8];
    const float* i_tf = (const float*)d_in[9];
    const float* i_tc = (const float*)d_in[10];
    const float* W_ri = (const float*)d_in[11];
    const float* b_ri = (const float*)d_in[12];
    const float* W_ir = (const float*)d_in[13];
    const float* b_ir = (const float*)d_in[14];
    const float* fg   = (const float*)d_in[15];
    const float* mem  = (const float*)d_in[16];
    const float* W_o1 = (const float*)d_in[17];
    const float* b_o1 = (const float*)d_in[18];
    const float* W_o2 = (const float*)d_in[19];
    const float* b_o2 = (const float*)d_in[20];
    float* out = (float*)d_out;
    float* ws  = (float*)d_ws;

    const int B = in_sizes[0] / 6;
    const int npairs = B >> 1;

    float* cst      = ws;        // fallback scalars
    float* partials = ws + 64;

    // ---- primary: cooperative single-pass kernel ----
    // 256 thr/block, 4 pairs (8 rows) per thread -> NB blocks; co-resident at 4 blocks/CU.
    int NB = (npairs + 1023) >> 10;
    if (NB < 1) NB = 1;
    const bool coop_ok =
        (NB <= 1024) && (ws_size >= (size_t)(64 + 2*NB) * sizeof(float));

    if (coop_ok) {
        int Bv = B;
        void* args[] = {
            (void*)&x, (void*)&W_in, (void*)&b_in, (void*)&r_w, (void*)&r_b,
            (void*)&r_tf, (void*)&r_tc, (void*)&i_w, (void*)&i_b, (void*)&i_tf,
            (void*)&i_tc, (void*)&W_ri, (void*)&b_ri, (void*)&W_ir, (void*)&b_ir,
            (void*)&fg, (void*)&mem, (void*)&W_o1, (void*)&b_o1, (void*)&W_o2,
            (void*)&b_o2, (void*)&partials, (void*)&out, (void*)&Bv
        };
        hipError_t e = hipLaunchCooperativeKernel((void*)k_fused, dim3(NB), dim3(256),
                                                  args, 0, stream);
        if (e == hipSuccess) return;
    }

    // ---- fallback: 3-kernel path ----
    int NB1 = 2048;
    const long cap = (long)(ws_size / 4) - 64;
    if (cap < 2L * NB1) NB1 = (int)(cap / 2);
    if (NB1 < 1) NB1 = 1;

    k_pass1<<<NB1, 256, 0, stream>>>(x, W_in, b_in, r_tf, partials, B);
    k_mid<<<1, 256, 0, stream>>>(partials, NB1, B, i_w, i_b, i_tf, i_tc,
                                 W_ri, b_ri, W_ir, b_ir, fg, mem, r_tc, cst);
    int NB2 = (B + 256*4 - 1) / (256*4);
    if (NB2 < 1) NB2 = 1;
    k_pass2<<<NB2, 256, 0, stream>>>(x, W_in, b_in, r_w, r_b, r_tf,
                                     W_o1, b_o1, W_o2, b_o2, cst, out, B);
}

// Round 4
// 53.051 us; speedup vs baseline: 2.6841x; 2.6841x over previous
//
#include <hip/hip_runtime.h>
#include <math.h>

#define TWO_PI_F 6.2831853071795864769f

// Branchless erf-based exact GELU (A&S 7.1.26, |err|<=1.5e-7).
__device__ __forceinline__ float gelu_f(float v) {
    const float y  = v * 0.70710678118654752f;
    const float ay = fabsf(y);
    const float t  = __builtin_amdgcn_rcpf(fmaf(0.3275911f, ay, 1.0f));
    const float e  = __builtin_amdgcn_exp2f(-1.4426950408889634f * y * y);
    float p = fmaf(1.061405429f, t, -1.453152027f);
    p = fmaf(p, t, 1.421413741f);
    p = fmaf(p, t, -0.284496736f);
    p = fmaf(p, t, 0.254829592f);
    const float erf_abs = 1.0f - p * t * e;
    const float erf_v   = copysignf(erf_abs, v);
    const float hv = 0.5f * v;
    return fmaf(hv, erf_v, hv);
}

// ============ kernel 1: batch |lo_n| sums; block 0 folds internal path ============
// cst layout (floats): [2]=sr  [8..23]=M4 (g^2*W_ir@W_ri)  [24..27]=cvec
__global__ __launch_bounds__(256) void k_sum(
    const float* __restrict__ x,
    const float* __restrict__ W_in, const float* __restrict__ b_in,
    const float* __restrict__ r_tf, const float* __restrict__ r_tc,
    const float* __restrict__ i_w,  const float* __restrict__ i_b,
    const float* __restrict__ i_tf, const float* __restrict__ i_tc,
    const float* __restrict__ W_ri, const float* __restrict__ b_ri,
    const float* __restrict__ W_ir, const float* __restrict__ b_ir,
    const float* __restrict__ flow_gate, const float* __restrict__ mem,
    float2* __restrict__ partials, float* __restrict__ cst, int B)
{
    const int tid = threadIdx.x;
    __shared__ float s_hc[16];
    __shared__ float s_red[8];

    // ---- fold of the constant internal path (weights-only), block 0 ----
    if (blockIdx.x == 0 && tid < 64) {
        const int j = tid & 15;
        float base = i_b[j];
#pragma unroll
        for (int k = 0; k < 16; ++k) base = fmaf(i_w[j*16 + k], mem[k], base);
        float corr = 0.f;
#pragma unroll
        for (int n = 0; n < 3; ++n) {
            float lo = 0.f;
#pragma unroll
            for (int k = 0; k < 16; ++k) lo = fmaf(i_tf[n*256 + j*16 + k], mem[k], lo);
            float a = fabsf(lo);
            a += __shfl_xor(a, 1); a += __shfl_xor(a, 2); a += __shfl_xor(a, 4); a += __shfl_xor(a, 8);
            const float mean = a * (1.0f/16.0f);
            const float phase = TWO_PI_F * (float)(n+1) * lo / (mean + 1e-8f);
            corr = fmaf(sinf(phase), lo / (float)(n+1), corr);
        }
        const float sc = 1.0f / (1.0f + expf(-i_tc[0]));
        const float t = fmaf(sc, corr, base);
        float mu = t;
        mu += __shfl_xor(mu, 1); mu += __shfl_xor(mu, 2); mu += __shfl_xor(mu, 4); mu += __shfl_xor(mu, 8);
        mu *= (1.0f/16.0f);
        const float d = t - mu;
        float v = d*d;
        v += __shfl_xor(v, 1); v += __shfl_xor(v, 2); v += __shfl_xor(v, 4); v += __shfl_xor(v, 8);
        v *= (1.0f/16.0f);
        const float h = gelu_f(d * rsqrtf(v + 1e-5f));
        if (tid < 16) s_hc[j] = h;
    }
    __syncthreads();
    if (blockIdx.x == 0) {
        const float g = 1.0f / (1.0f + expf(-flow_gate[0]));
        if (tid < 4) {
            float acc = 0.f;
#pragma unroll
            for (int m = 0; m < 16; ++m) acc = fmaf(W_ir[tid*16 + m], fmaf(g, b_ri[m], s_hc[m]), acc);
            cst[24 + tid] = g * (acc + b_ir[tid]);
        }
        if (tid < 16) {
            const int l = tid >> 2, j = tid & 3;
            float M = 0.f;
#pragma unroll
            for (int m = 0; m < 16; ++m) M = fmaf(W_ir[l*16 + m], W_ri[m*4 + j], M);
            cst[8 + tid] = g * g * M;
        }
        if (tid == 0) cst[2] = 1.0f / (1.0f + expf(-r_tc[0]));
    }

    // ---- batch sums of |lo0|, |lo1| ----
    const int npairs = B >> 1;
    const int TT = gridDim.x * blockDim.x;
    const int gtid = blockIdx.x * blockDim.x + tid;
    float s0 = 0.f, s1 = 0.f;
    for (int p = gtid; p < npairs; p += TT) {
        const float4* xp = (const float4*)(x + (size_t)p * 12);
        float4 q0 = xp[0], q1 = xp[1], q2 = xp[2];
        float xv[2][6] = {{q0.x, q0.y, q0.z, q0.w, q1.x, q1.y},
                          {q1.z, q1.w, q2.x, q2.y, q2.z, q2.w}};
#pragma unroll
        for (int r = 0; r < 2; ++r) {
            float xr[4];
#pragma unroll
            for (int j = 0; j < 4; ++j) {
                float a = b_in[j];
#pragma unroll
                for (int k = 0; k < 6; ++k) a = fmaf(W_in[j*6+k], xv[r][k], a);
                xr[j] = gelu_f(a);
            }
#pragma unroll
            for (int j = 0; j < 4; ++j) {
                float l0 = 0.f, l1 = 0.f;
#pragma unroll
                for (int k = 0; k < 4; ++k) {
                    l0 = fmaf(r_tf[j*4+k],      xr[k], l0);
                    l1 = fmaf(r_tf[16 + j*4+k], xr[k], l1);
                }
                s0 += fabsf(l0);
                s1 += fabsf(l1);
            }
        }
    }
    if ((B & 1) && gtid == 0) {
        const float* xs = x + (size_t)(B-1) * 6;
        float xr[4];
#pragma unroll
        for (int j = 0; j < 4; ++j) {
            float a = b_in[j];
#pragma unroll
            for (int k = 0; k < 6; ++k) a = fmaf(W_in[j*6+k], xs[k], a);
            xr[j] = gelu_f(a);
        }
#pragma unroll
        for (int j = 0; j < 4; ++j) {
            float l0 = 0.f, l1 = 0.f;
#pragma unroll
            for (int k = 0; k < 4; ++k) {
                l0 = fmaf(r_tf[j*4+k],      xr[k], l0);
                l1 = fmaf(r_tf[16 + j*4+k], xr[k], l1);
            }
            s0 += fabsf(l0);
            s1 += fabsf(l1);
        }
    }
#pragma unroll
    for (int off = 32; off > 0; off >>= 1) {
        s0 += __shfl_down(s0, off);
        s1 += __shfl_down(s1, off);
    }
    if ((tid & 63) == 0) { s_red[(tid>>6)*2] = s0; s_red[(tid>>6)*2+1] = s1; }
    __syncthreads();
    if (tid == 0) {
        partials[blockIdx.x] = make_float2(s_red[0]+s_red[2]+s_red[4]+s_red[6],
                                           s_red[1]+s_red[3]+s_red[5]+s_red[7]);
    }
}

// ============ kernel 2: per-block partial reduce + full per-row pipeline ============
__global__ __launch_bounds__(256) void k_main(
    const float* __restrict__ x,
    const float* __restrict__ W_in, const float* __restrict__ b_in,
    const float* __restrict__ r_w,  const float* __restrict__ r_b,
    const float* __restrict__ r_tf,
    const float* __restrict__ W_o1, const float* __restrict__ b_o1,
    const float* __restrict__ W_o2, const float* __restrict__ b_o2,
    const float2* __restrict__ partials, int nb,
    const float* __restrict__ cst,
    float* __restrict__ out, int B)
{
    const int tid = threadIdx.x;
    __shared__ float s_red[8];
    __shared__ float s_c[2];

    // ---- redundant deterministic reduce of block partials (L2-broadcast, 8 KB) ----
    float t0 = 0.f, t1 = 0.f;
    for (int k = tid; k < nb; k += 256) {
        const float2 pr = partials[k];
        t0 += pr.x; t1 += pr.y;
    }
#pragma unroll
    for (int off = 32; off > 0; off >>= 1) {
        t0 += __shfl_down(t0, off);
        t1 += __shfl_down(t1, off);
    }
    if ((tid & 63) == 0) { s_red[(tid>>6)*2] = t0; s_red[(tid>>6)*2+1] = t1; }
    __syncthreads();
    if (tid == 0) {
        const float u0 = s_red[0]+s_red[2]+s_red[4]+s_red[6];
        const float u1 = s_red[1]+s_red[3]+s_red[5]+s_red[7];
        const float m0 = u0 / (4.0f * (float)B);
        const float m1 = u1 / (4.0f * (float)B);
        s_c[0] = TWO_PI_F * 1.0f / (m0 + 1e-8f);
        s_c[1] = TWO_PI_F * 2.0f / (m1 + 1e-8f);
    }
    __syncthreads();
    const float c0 = s_c[0], c1 = s_c[1];
    const float sr = cst[2];

    float m4[16], cvec[4];
#pragma unroll
    for (int i = 0; i < 16; ++i) m4[i] = cst[8 + i];
#pragma unroll
    for (int i = 0; i < 4; ++i)  cvec[i] = cst[24 + i];

    // ---- per-row pipeline, 1 pair (2 rows) per iteration ----
    const int npairs = B >> 1;
    const int TT = gridDim.x * blockDim.x;
    const int gtid = blockIdx.x * blockDim.x + tid;

    for (int p = gtid; p < npairs; p += TT) {
        const float4* xp = (const float4*)(x + (size_t)p * 12);
        float4 q0 = xp[0], q1 = xp[1], q2 = xp[2];
        float xv[2][6] = {{q0.x, q0.y, q0.z, q0.w, q1.x, q1.y},
                          {q1.z, q1.w, q2.x, q2.y, q2.z, q2.w}};
#pragma unroll
        for (int r = 0; r < 2; ++r) {
            float xr[4];
#pragma unroll
            for (int j = 0; j < 4; ++j) {
                float a = b_in[j];
#pragma unroll
                for (int k = 0; k < 6; ++k) a = fmaf(W_in[j*6+k], xv[r][k], a);
                xr[j] = gelu_f(a);
            }
            float t[4];
#pragma unroll
            for (int j = 0; j < 4; ++j) {
                float l0 = 0.f, l1 = 0.f, bse = r_b[j];
#pragma unroll
                for (int k = 0; k < 4; ++k) {
                    l0  = fmaf(r_tf[j*4+k],      xr[k], l0);
                    l1  = fmaf(r_tf[16 + j*4+k], xr[k], l1);
                    bse = fmaf(r_w[j*4+k],       xr[k], bse);
                }
                const float corr = __sinf(c0 * l0) * l0 + 0.5f * __sinf(c1 * l1) * l1;
                t[j] = fmaf(sr, corr, bse);
            }
            const float mu = 0.25f * (t[0] + t[1] + t[2] + t[3]);
            float d0 = t[0]-mu, d1 = t[1]-mu, d2 = t[2]-mu, d3 = t[3]-mu;
            const float var = 0.25f * (d0*d0 + d1*d1 + d2*d2 + d3*d3);
            const float inv = rsqrtf(var + 1e-5f);
            float hr[4] = { gelu_f(d0*inv), gelu_f(d1*inv), gelu_f(d2*inv), gelu_f(d3*inv) };

            float h2[4];
#pragma unroll
            for (int l = 0; l < 4; ++l) {
                float a = hr[l] + cvec[l];
#pragma unroll
                for (int j = 0; j < 4; ++j) a = fmaf(m4[l*4+j], hr[j], a);
                h2[l] = a;
            }
            float hid[8];
#pragma unroll
            for (int h = 0; h < 8; ++h) {
                float a = b_o1[h];
#pragma unroll
                for (int l = 0; l < 4; ++l) a = fmaf(W_o1[h*4+l], h2[l], a);
                hid[h] = gelu_f(a);
            }
            float o[4];
#pragma unroll
            for (int oo = 0; oo < 4; ++oo) {
                float a = b_o2[oo];
#pragma unroll
                for (int h = 0; h < 8; ++h) a = fmaf(W_o2[oo*8+h], hid[h], a);
                o[oo] = a;
            }
            ((float4*)out)[(size_t)2*p + r] = make_float4(o[0], o[1], o[2], o[3]);
        }
    }

    if ((B & 1) && gtid == 0) {
        const float* xs = x + (size_t)(B-1) * 6;
        float xr[4];
#pragma unroll
        for (int j = 0; j < 4; ++j) {
            float a = b_in[j];
#pragma unroll
            for (int k = 0; k < 6; ++k) a = fmaf(W_in[j*6+k], xs[k], a);
            xr[j] = gelu_f(a);
        }
        float t[4];
#pragma unroll
        for (int j = 0; j < 4; ++j) {
            float l0 = 0.f, l1 = 0.f, bse = r_b[j];
#pragma unroll
            for (int k = 0; k < 4; ++k) {
                l0  = fmaf(r_tf[j*4+k],      xr[k], l0);
                l1  = fmaf(r_tf[16 + j*4+k], xr[k], l1);
                bse = fmaf(r_w[j*4+k],       xr[k], bse);
            }
            const float corr = __sinf(c0 * l0) * l0 + 0.5f * __sinf(c1 * l1) * l1;
            t[j] = fmaf(sr, corr, bse);
        }
        const float mu = 0.25f * (t[0] + t[1] + t[2] + t[3]);
        float d0 = t[0]-mu, d1 = t[1]-mu, d2 = t[2]-mu, d3 = t[3]-mu;
        const float var = 0.25f * (d0*d0 + d1*d1 + d2*d2 + d3*d3);
        const float inv = rsqrtf(var + 1e-5f);
        float hr[4] = { gelu_f(d0*inv), gelu_f(d1*inv), gelu_f(d2*inv), gelu_f(d3*inv) };
        float h2[4];
#pragma unroll
        for (int l = 0; l < 4; ++l) {
            float a = hr[l] + cvec[l];
#pragma unroll
            for (int j = 0; j < 4; ++j) a = fmaf(m4[l*4+j], hr[j], a);
            h2[l] = a;
        }
        float hid[8];
#pragma unroll
        for (int h = 0; h < 8; ++h) {
            float a = b_o1[h];
#pragma unroll
            for (int l = 0; l < 4; ++l) a = fmaf(W_o1[h*4+l], h2[l], a);
            hid[h] = gelu_f(a);
        }
        float o[4];
#pragma unroll
        for (int oo = 0; oo < 4; ++oo) {
            float a = b_o2[oo];
#pragma unroll
            for (int h = 0; h < 8; ++h) a = fmaf(W_o2[oo*8+h], hid[h], a);
            o[oo] = a;
        }
        ((float4*)out)[(size_t)B - 1] = make_float4(o[0], o[1], o[2], o[3]);
    }
}

extern "C" void kernel_launch(void* const* d_in, const int* in_sizes, int n_in,
                              void* d_out, int out_size, void* d_ws, size_t ws_size,
                              hipStream_t stream)
{
    const float* x    = (const float*)d_in[0];
    const float* W_in = (const float*)d_in[1];
    const float* b_in = (const float*)d_in[2];
    const float* r_w  = (const float*)d_in[3];
    const float* r_b  = (const float*)d_in[4];
    const float* r_tf = (const float*)d_in[5];
    const float* r_tc = (const float*)d_in[6];
    const float* i_w  = (const float*)d_in[7];
    const float* i_b  = (const float*)d_in[8];
    const float* i_tf = (const float*)d_in[9];
    const float* i_tc = (const float*)d_in[10];
    const float* W_ri = (const float*)d_in[11];
    const float* b_ri = (const float*)d_in[12];
    const float* W_ir = (const float*)d_in[13];
    const float* b_ir = (const float*)d_in[14];
    const float* fg   = (const float*)d_in[15];
    const float* mem  = (const float*)d_in[16];
    const float* W_o1 = (const float*)d_in[17];
    const float* b_o1 = (const float*)d_in[18];
    const float* W_o2 = (const float*)d_in[19];
    const float* b_o2 = (const float*)d_in[20];
    float* out = (float*)d_out;
    float* ws  = (float*)d_ws;

    const int B = in_sizes[0] / 6;

    // ws layout (floats): [0..63] = cst, [64..] = partials (float2 per block)
    int NB1 = 1024;
    const long cap = (long)(ws_size / 4) - 64;
    if (cap < 2L * NB1) NB1 = (int)(cap / 2);
    if (NB1 < 1) NB1 = 1;
    float*  cst      = ws;
    float2* partials = (float2*)(ws + 64);

    k_sum<<<NB1, 256, 0, stream>>>(x, W_in, b_in, r_tf, r_tc, i_w, i_b, i_tf, i_tc,
                                   W_ri, b_ri, W_ir, b_ir, fg, mem, partials, cst, B);

    int NB2 = 2048;
    const int npairs = B >> 1;
    if (NB2 * 256 > npairs + 255) NB2 = (npairs + 255) / 256;
    if (NB2 < 1) NB2 = 1;
    k_main<<<NB2, 256, 0, stream>>>(x, W_in, b_in, r_w, r_b, r_tf,
                                    W_o1, b_o1, W_o2, b_o2,
                                    partials, NB1, cst, out, B);
}

// Round 6
// 49.532 us; speedup vs baseline: 2.8748x; 1.0710x over previous
//
#include <hip/hip_runtime.h>
#include <math.h>

#define TWO_PI_F 6.2831853071795864769f

typedef float v2f __attribute__((ext_vector_type(2)));
typedef float v4f __attribute__((ext_vector_type(4)));

static __device__ __forceinline__ v2f v2s(float s) { return (v2f){s, s}; }

static __device__ __forceinline__ v2f fma2(v2f a, v2f b, v2f c) {
#if __has_builtin(__builtin_elementwise_fma)
    return __builtin_elementwise_fma(a, b, c);
#else
    return (v2f){ fmaf(a.x, b.x, c.x), fmaf(a.y, b.y, c.y) };
#endif
}

static __device__ __forceinline__ float sin_rev(float x) {   // sin(2*pi*x)
#if __has_builtin(__builtin_amdgcn_sinf)
    return __builtin_amdgcn_sinf(x);
#else
    return __sinf(TWO_PI_F * x);
#endif
}

// A&S 7.1.25 erf (|err|<=2.5e-5), branchless; exact-GELU substitute.
static __device__ __forceinline__ float gelu_s(float v) {
    const float y  = v * 0.70710678118654752f;
    const float ay = fabsf(y);
    const float t  = __builtin_amdgcn_rcpf(fmaf(0.47047f, ay, 1.0f));
    const float e  = __builtin_amdgcn_exp2f(y * y * -1.4426950408889634f);
    float p = fmaf(0.7478556f, t, -0.0958798f);
    p = fmaf(p, t, 0.3480242f);
    const float erf_abs = 1.0f - p * t * e;
    const float erf_v   = __builtin_copysignf(erf_abs, v);
    const float hv = 0.5f * v;
    return fmaf(hv, erf_v, hv);
}

static __device__ __forceinline__ v2f gelu2(v2f v) {
    v2f y  = v * 0.70710678118654752f;
    v2f ay = (v2f){ fabsf(y.x), fabsf(y.y) };
    v2f td = fma2(v2s(0.47047f), ay, v2s(1.0f));
    v2f t  = (v2f){ __builtin_amdgcn_rcpf(td.x), __builtin_amdgcn_rcpf(td.y) };
    v2f yy = y * y;
    v2f e  = (v2f){ __builtin_amdgcn_exp2f(yy.x * -1.4426950408889634f),
                    __builtin_amdgcn_exp2f(yy.y * -1.4426950408889634f) };
    v2f p  = fma2(v2s(0.7478556f), t, v2s(-0.0958798f));
    p = fma2(p, t, v2s(0.3480242f));
    v2f erfabs = v2s(1.0f) - (p * t) * e;
    v2f erf = (v2f){ __builtin_copysignf(erfabs.x, v.x),
                     __builtin_copysignf(erfabs.y, v.y) };
    v2f hv = v * 0.5f;
    return fma2(hv, erf, hv);
}

// cst layout (floats): [0]=sr  [8..23]=tfs0(sr*tf0) [24..39]=tfs1(0.5*sr*tf1)
//                      [40..71]=W1e(8x4) [72..79]=b1e(8)
// ============ kernel 1: batch |lo_n| sums; block 0 folds all constants ============
__global__ __launch_bounds__(256, 8) void k_sum(
    const float* __restrict__ x,
    const float* __restrict__ W_in, const float* __restrict__ b_in,
    const float* __restrict__ r_tf, const float* __restrict__ r_tc,
    const float* __restrict__ i_w,  const float* __restrict__ i_b,
    const float* __restrict__ i_tf, const float* __restrict__ i_tc,
    const float* __restrict__ W_ri, const float* __restrict__ b_ri,
    const float* __restrict__ W_ir, const float* __restrict__ b_ir,
    const float* __restrict__ flow_gate, const float* __restrict__ mem,
    const float* __restrict__ W_o1, const float* __restrict__ b_o1,
    float2* __restrict__ partials, float* __restrict__ cst, int B)
{
    const int tid = threadIdx.x;
    __shared__ float s_hc[16], s_cv[4], s_m4[16], s_red[8];

    if (blockIdx.x == 0) {
        // constant internal path (weights-only)
        if (tid < 64) {
            const int j = tid & 15;
            float base = i_b[j];
#pragma unroll
            for (int k = 0; k < 16; ++k) base = fmaf(i_w[j*16 + k], mem[k], base);
            float corr = 0.f;
#pragma unroll
            for (int n = 0; n < 3; ++n) {
                float lo = 0.f;
#pragma unroll
                for (int k = 0; k < 16; ++k) lo = fmaf(i_tf[n*256 + j*16 + k], mem[k], lo);
                float a = fabsf(lo);
                a += __shfl_xor(a, 1); a += __shfl_xor(a, 2);
                a += __shfl_xor(a, 4); a += __shfl_xor(a, 8);
                const float mean = a * (1.0f/16.0f);
                const float phase = TWO_PI_F * (float)(n+1) * lo / (mean + 1e-8f);
                corr = fmaf(sinf(phase), lo / (float)(n+1), corr);
            }
            const float sc = 1.0f / (1.0f + expf(-i_tc[0]));
            const float t = fmaf(sc, corr, base);
            float mu = t;
            mu += __shfl_xor(mu, 1); mu += __shfl_xor(mu, 2);
            mu += __shfl_xor(mu, 4); mu += __shfl_xor(mu, 8);
            mu *= (1.0f/16.0f);
            const float d = t - mu;
            float v = d*d;
            v += __shfl_xor(v, 1); v += __shfl_xor(v, 2);
            v += __shfl_xor(v, 4); v += __shfl_xor(v, 8);
            v *= (1.0f/16.0f);
            const float h = gelu_s(d * rsqrtf(v + 1e-5f));
            if (tid < 16) s_hc[j] = h;
        }
        __syncthreads();
        const float g  = 1.0f / (1.0f + expf(-flow_gate[0]));
        const float sr = 1.0f / (1.0f + expf(-r_tc[0]));
        if (tid < 4) {
            float acc = 0.f;
#pragma unroll
            for (int m = 0; m < 16; ++m)
                acc = fmaf(W_ir[tid*16 + m], fmaf(g, b_ri[m], s_hc[m]), acc);
            s_cv[tid] = g * (acc + b_ir[tid]);
        }
        if (tid < 16) {
            const int l = tid >> 2, j = tid & 3;
            float M = 0.f;
#pragma unroll
            for (int m = 0; m < 16; ++m) M = fmaf(W_ir[l*16 + m], W_ri[m*4 + j], M);
            s_m4[tid] = g * g * M;
            cst[8  + tid] = sr * r_tf[tid];             // tfs0
            cst[24 + tid] = 0.5f * sr * r_tf[16 + tid]; // tfs1
        }
        if (tid == 0) cst[0] = sr;
        __syncthreads();
        if (tid < 32) {   // W1e = W_o1 @ (I + M4)
            const int h = tid >> 2, j = tid & 3;
            float we = 0.f;
#pragma unroll
            for (int l = 0; l < 4; ++l)
                we = fmaf(W_o1[h*4 + l], ((l == j) ? 1.0f : 0.0f) + s_m4[l*4 + j], we);
            cst[40 + tid] = we;
        }
        if (tid < 8) {    // b1e = b_o1 + W_o1 @ cvec
            float be = b_o1[tid];
#pragma unroll
            for (int l = 0; l < 4; ++l) be = fmaf(W_o1[tid*4 + l], s_cv[l], be);
            cst[72 + tid] = be;
        }
    }

    // ---- batch sums of |lo0|, |lo1| over row pairs (packed 2-wide) ----
    const int npairs = B >> 1;
    const int TT = gridDim.x * blockDim.x;
    const int gtid = blockIdx.x * blockDim.x + tid;
    v2f a0 = v2s(0.f), a1 = v2s(0.f);
    for (int p = gtid; p < npairs; p += TT) {
        const float4* xp = (const float4*)(x + (size_t)p * 12);
        float4 q0 = xp[0], q1 = xp[1], q2 = xp[2];
        v2f xv[6] = { {q0.x, q1.z}, {q0.y, q1.w}, {q0.z, q2.x},
                      {q0.w, q2.y}, {q1.x, q2.z}, {q1.y, q2.w} };
        v2f xr[4];
#pragma unroll
        for (int j = 0; j < 4; ++j) {
            v2f a = v2s(b_in[j]);
#pragma unroll
            for (int k = 0; k < 6; ++k) a = fma2(v2s(W_in[j*6+k]), xv[k], a);
            xr[j] = gelu2(a);
        }
#pragma unroll
        for (int j = 0; j < 4; ++j) {
            v2f l0 = v2s(0.f), l1 = v2s(0.f);
#pragma unroll
            for (int k = 0; k < 4; ++k) {
                l0 = fma2(v2s(r_tf[j*4+k]),      xr[k], l0);
                l1 = fma2(v2s(r_tf[16 + j*4+k]), xr[k], l1);
            }
            a0 += (v2f){ fabsf(l0.x), fabsf(l0.y) };
            a1 += (v2f){ fabsf(l1.x), fabsf(l1.y) };
        }
    }
    float s0 = a0.x + a0.y, s1 = a1.x + a1.y;
    if ((B & 1) && gtid == 0) {
        const float* xs = x + (size_t)(B-1) * 6;
        float xr[4];
#pragma unroll
        for (int j = 0; j < 4; ++j) {
            float a = b_in[j];
#pragma unroll
            for (int k = 0; k < 6; ++k) a = fmaf(W_in[j*6+k], xs[k], a);
            xr[j] = gelu_s(a);
        }
#pragma unroll
        for (int j = 0; j < 4; ++j) {
            float l0 = 0.f, l1 = 0.f;
#pragma unroll
            for (int k = 0; k < 4; ++k) {
                l0 = fmaf(r_tf[j*4+k],      xr[k], l0);
                l1 = fmaf(r_tf[16 + j*4+k], xr[k], l1);
            }
            s0 += fabsf(l0);
            s1 += fabsf(l1);
        }
    }
#pragma unroll
    for (int off = 32; off > 0; off >>= 1) {
        s0 += __shfl_down(s0, off);
        s1 += __shfl_down(s1, off);
    }
    if ((tid & 63) == 0) { s_red[(tid>>6)*2] = s0; s_red[(tid>>6)*2+1] = s1; }
    __syncthreads();
    if (tid == 0) {
        partials[blockIdx.x] = make_float2(s_red[0]+s_red[2]+s_red[4]+s_red[6],
                                           s_red[1]+s_red[3]+s_red[5]+s_red[7]);
    }
}

// ============ kernel 2: partial reduce + full per-row-pair pipeline (packed) ========
__global__ __launch_bounds__(256, 4) void k_main(
    const float* __restrict__ x,
    const float* __restrict__ W_in, const float* __restrict__ b_in,
    const float* __restrict__ r_w,  const float* __restrict__ r_b,
    const float* __restrict__ W_o2, const float* __restrict__ b_o2,
    const float2* __restrict__ partials, int nb,
    const float* __restrict__ cst,
    float* __restrict__ out, int B)
{
    const int tid = threadIdx.x;
    __shared__ float s_red[8];
    __shared__ float s_c[2];

    // redundant deterministic reduce of block partials
    float t0 = 0.f, t1 = 0.f;
    for (int k = tid; k < nb; k += 256) {
        const float2 pr = partials[k];
        t0 += pr.x; t1 += pr.y;
    }
#pragma unroll
    for (int off = 32; off > 0; off >>= 1) {
        t0 += __shfl_down(t0, off);
        t1 += __shfl_down(t1, off);
    }
    if ((tid & 63) == 0) { s_red[(tid>>6)*2] = t0; s_red[(tid>>6)*2+1] = t1; }
    __syncthreads();
    const float sr = cst[0];
    if (tid == 0) {
        const float u0 = s_red[0]+s_red[2]+s_red[4]+s_red[6];
        const float u1 = s_red[1]+s_red[3]+s_red[5]+s_red[7];
        const float m0 = u0 / (4.0f * (float)B);
        const float m1 = u1 / (4.0f * (float)B);
        // revolution-domain phase constants; 2*pi cancels against v_sin's domain
        s_c[0] = 1.0f / ((m0 + 1e-8f) * sr);
        s_c[1] = 4.0f / ((m1 + 1e-8f) * sr);
    }
    __syncthreads();
    const float C0 = s_c[0], C1 = s_c[1];

    const int npairs = B >> 1;
    const int TT = gridDim.x * blockDim.x;
    const int gtid = blockIdx.x * blockDim.x + tid;

    for (int p = gtid; p < npairs; p += TT) {
        const float4* xp = (const float4*)(x + (size_t)p * 12);
        float4 q0 = xp[0], q1 = xp[1], q2 = xp[2];
        v2f xv[6] = { {q0.x, q1.z}, {q0.y, q1.w}, {q0.z, q2.x},
                      {q0.w, q2.y}, {q1.x, q2.z}, {q1.y, q2.w} };

        v2f xr[4];
#pragma unroll
        for (int j = 0; j < 4; ++j) {
            v2f a = v2s(b_in[j]);
#pragma unroll
            for (int k = 0; k < 6; ++k) a = fma2(v2s(W_in[j*6+k]), xv[k], a);
            xr[j] = gelu2(a);
        }

        v2f t[4];
#pragma unroll
        for (int j = 0; j < 4; ++j) {
            v2f L0 = v2s(0.f), L1 = v2s(0.f), bse = v2s(r_b[j]);
#pragma unroll
            for (int k = 0; k < 4; ++k) {
                L0  = fma2(v2s(cst[8  + j*4+k]), xr[k], L0);   // sr-scaled tf0
                L1  = fma2(v2s(cst[24 + j*4+k]), xr[k], L1);   // 0.5*sr-scaled tf1
                bse = fma2(v2s(r_w[j*4+k]),      xr[k], bse);
            }
            v2f sa = (v2f){ sin_rev(C0 * L0.x), sin_rev(C0 * L0.y) };
            v2f sb = (v2f){ sin_rev(C1 * L1.x), sin_rev(C1 * L1.y) };
            t[j] = fma2(sa, L0, fma2(sb, L1, bse));
        }

        const v2f mu = (t[0] + t[1] + t[2] + t[3]) * 0.25f;
        v2f d0 = t[0]-mu, d1 = t[1]-mu, d2 = t[2]-mu, d3 = t[3]-mu;
        v2f var = d0*d0;
        var = fma2(d1, d1, var);
        var = fma2(d2, d2, var);
        var = fma2(d3, d3, var);
        var = var * 0.25f + 1e-5f;
        const v2f inv = (v2f){ __builtin_amdgcn_rsqf(var.x), __builtin_amdgcn_rsqf(var.y) };
        v2f hr[4] = { gelu2(d0*inv), gelu2(d1*inv), gelu2(d2*inv), gelu2(d3*inv) };

        v2f hid[8];
#pragma unroll
        for (int h = 0; h < 8; ++h) {
            v2f a = v2s(cst[72 + h]);                          // b1e
#pragma unroll
            for (int j = 0; j < 4; ++j) a = fma2(v2s(cst[40 + h*4+j]), hr[j], a); // W1e
            hid[h] = gelu2(a);
        }
        v2f o[4];
#pragma unroll
        for (int oo = 0; oo < 4; ++oo) {
            v2f a = v2s(b_o2[oo]);
#pragma unroll
            for (int h = 0; h < 8; ++h) a = fma2(v2s(W_o2[oo*8+h]), hid[h], a);
            o[oo] = a;
        }
        // nontemporal stores through native clang vector type (not HIP_vector_type)
        v4f r0 = (v4f){ o[0].x, o[1].x, o[2].x, o[3].x };
        v4f r1 = (v4f){ o[0].y, o[1].y, o[2].y, o[3].y };
        __builtin_nontemporal_store(r0, (v4f*)out + (size_t)2*p);
        __builtin_nontemporal_store(r1, (v4f*)out + (size_t)2*p + 1);
    }

    if ((B & 1) && gtid == 0) {   // scalar tail row
        const float* xs = x + (size_t)(B-1) * 6;
        float xr[4];
#pragma unroll
        for (int j = 0; j < 4; ++j) {
            float a = b_in[j];
#pragma unroll
            for (int k = 0; k < 6; ++k) a = fmaf(W_in[j*6+k], xs[k], a);
            xr[j] = gelu_s(a);
        }
        float t[4];
#pragma unroll
        for (int j = 0; j < 4; ++j) {
            float L0 = 0.f, L1 = 0.f, bse = r_b[j];
#pragma unroll
            for (int k = 0; k < 4; ++k) {
                L0  = fmaf(cst[8  + j*4+k], xr[k], L0);
                L1  = fmaf(cst[24 + j*4+k], xr[k], L1);
                bse = fmaf(r_w[j*4+k],      xr[k], bse);
            }
            t[j] = fmaf(sin_rev(C0*L0), L0, fmaf(sin_rev(C1*L1), L1, bse));
        }
        const float mu = 0.25f * (t[0]+t[1]+t[2]+t[3]);
        float d0=t[0]-mu, d1=t[1]-mu, d2=t[2]-mu, d3=t[3]-mu;
        const float var = 0.25f * (d0*d0 + d1*d1 + d2*d2 + d3*d3);
        const float inv = __builtin_amdgcn_rsqf(var + 1e-5f);
        float hr[4] = { gelu_s(d0*inv), gelu_s(d1*inv), gelu_s(d2*inv), gelu_s(d3*inv) };
        float hid[8];
#pragma unroll
        for (int h = 0; h < 8; ++h) {
            float a = cst[72 + h];
#pragma unroll
            for (int j = 0; j < 4; ++j) a = fmaf(cst[40 + h*4+j], hr[j], a);
            hid[h] = gelu_s(a);
        }
        float o[4];
#pragma unroll
        for (int oo = 0; oo < 4; ++oo) {
            float a = b_o2[oo];
#pragma unroll
            for (int h = 0; h < 8; ++h) a = fmaf(W_o2[oo*8+h], hid[h], a);
            o[oo] = a;
        }
        ((float4*)out)[(size_t)B - 1] = make_float4(o[0], o[1], o[2], o[3]);
    }
}

extern "C" void kernel_launch(void* const* d_in, const int* in_sizes, int n_in,
                              void* d_out, int out_size, void* d_ws, size_t ws_size,
                              hipStream_t stream)
{
    const float* x    = (const float*)d_in[0];
    const float* W_in = (const float*)d_in[1];
    const float* b_in = (const float*)d_in[2];
    const float* r_w  = (const float*)d_in[3];
    const float* r_b  = (const float*)d_in[4];
    const float* r_tf = (const float*)d_in[5];
    const float* r_tc = (const float*)d_in[6];
    const float* i_w  = (const float*)d_in[7];
    const float* i_b  = (const float*)d_in[8];
    const float* i_tf = (const float*)d_in[9];
    const float* i_tc = (const float*)d_in[10];
    const float* W_ri = (const float*)d_in[11];
    const float* b_ri = (const float*)d_in[12];
    const float* W_ir = (const float*)d_in[13];
    const float* b_ir = (const float*)d_in[14];
    const float* fg   = (const float*)d_in[15];
    const float* mem  = (const float*)d_in[16];
    const float* W_o1 = (const float*)d_in[17];
    const float* b_o1 = (const float*)d_in[18];
    const float* W_o2 = (const float*)d_in[19];
    const float* b_o2 = (const float*)d_in[20];
    float* out = (float*)d_out;
    float* ws  = (float*)d_ws;

    const int B = in_sizes[0] / 6;
    const int npairs = B >> 1;

    // ws layout (floats): [0..127] = cst, [128..] = partials (float2 per block)
    int NB1 = 1024;
    const long cap = (long)(ws_size / 4) - 128;
    if (cap < 2L * NB1) NB1 = (int)(cap / 2);
    if (NB1 < 1) NB1 = 1;
    float*  cst      = ws;
    float2* partials = (float2*)(ws + 128);

    k_sum<<<NB1, 256, 0, stream>>>(x, W_in, b_in, r_tf, r_tc, i_w, i_b, i_tf, i_tc,
                                   W_ri, b_ri, W_ir, b_ir, fg, mem, W_o1, b_o1,
                                   partials, cst, B);

    int NB2 = (npairs + 511) / 512;   // 2 pairs per thread
    if (NB2 < 1) NB2 = 1;
    if (NB2 > 8192) NB2 = 8192;
    k_main<<<NB2, 256, 0, stream>>>(x, W_in, b_in, r_w, r_b, W_o2, b_o2,
                                    partials, NB1, cst, out, B);
}

// Round 7
// 46.899 us; speedup vs baseline: 3.0362x; 1.0561x over previous
//
#include <hip/hip_runtime.h>
#include <math.h>

#define TWO_PI_F 6.2831853071795864769f
#define LUT_N    2048
#define LUT_SCALE 170.66666667f   // 2048/12
#define LUT_STEP  0.005859375f    // 12/2048 (exact)

static __device__ __forceinline__ float sin_rev(float x) {   // sin(2*pi*x)
#if __has_builtin(__builtin_amdgcn_sinf)
    return __builtin_amdgcn_sinf(x);
#else
    return __sinf(TWO_PI_F * x);
#endif
}

// accurate branchless CDF for table build: 0.5*(1+erf(x/sqrt2)), A&S 7.1.26 (1.5e-7)
static __device__ __forceinline__ float cdf_acc(float v) {
    const float y  = v * 0.70710678118654752f;
    const float ay = fabsf(y);
    const float t  = __builtin_amdgcn_rcpf(fmaf(0.3275911f, ay, 1.0f));
    const float e  = __builtin_amdgcn_exp2f(y * y * -1.4426950408889634f);
    float p = fmaf(1.061405429f, t, -1.453152027f);
    p = fmaf(p, t, 1.421413741f);
    p = fmaf(p, t, -0.284496736f);
    p = fmaf(p, t, 0.254829592f);
    const float erf_abs = 1.0f - p * t * e;
    const float erf_v   = __builtin_copysignf(erf_abs, v);
    return fmaf(0.5f, erf_v, 0.5f);
}

// scalar exact-GELU (used only in tiny k_mid)
static __device__ __forceinline__ float gelu_s(float v) { return v * cdf_acc(v); }

// LDS-LUT gelu: x * lerp(t_i, t_i+dt_i)
static __device__ __forceinline__ float gelu_lut(float x, const float2* __restrict__ lut) {
    float f = fminf(fmaxf(fmaf(x, LUT_SCALE, 1024.0f), 0.0f), 2047.5f);
    float ff = floorf(f);
    float fr = f - ff;
    float2 e = lut[(int)ff];
    return x * fmaf(fr, e.y, e.x);
}

static __device__ __forceinline__ void build_lut(float2* lut, int tid) {
    for (int i = tid; i < LUT_N; i += 256) {
        float x0 = fmaf((float)i, LUT_STEP, -6.0f);
        float t0 = cdf_acc(x0);
        float t1 = cdf_acc(x0 + LUT_STEP);
        lut[i] = make_float2(t0, t1 - t0);
    }
}

// ============ kernel 1: batch sums of |lo0|,|lo1| (pure reduce) ============
__global__ __launch_bounds__(256, 8) void k_sum(
    const float* __restrict__ x,
    const float* __restrict__ W_in, const float* __restrict__ b_in,
    const float* __restrict__ r_tf,
    float2* __restrict__ partials, int B)
{
    const int tid = threadIdx.x;
    __shared__ float2 s_lut[LUT_N];
    __shared__ float s_red[8];
    build_lut(s_lut, tid);
    __syncthreads();

    const int npairs = B >> 1;
    const int TT = gridDim.x * blockDim.x;
    const int gtid = blockIdx.x * blockDim.x + tid;
    float s0 = 0.f, s1 = 0.f;

    for (int p = gtid; p < npairs; p += TT) {
        const float4* xp = (const float4*)(x + (size_t)p * 12);
        float4 q0 = xp[0], q1 = xp[1], q2 = xp[2];
        float xv[2][6] = {{q0.x, q0.y, q0.z, q0.w, q1.x, q1.y},
                          {q1.z, q1.w, q2.x, q2.y, q2.z, q2.w}};
#pragma unroll
        for (int r = 0; r < 2; ++r) {
            float xr[4];
#pragma unroll
            for (int j = 0; j < 4; ++j) {
                float a = b_in[j];
#pragma unroll
                for (int k = 0; k < 6; ++k) a = fmaf(W_in[j*6+k], xv[r][k], a);
                xr[j] = gelu_lut(a, s_lut);
            }
#pragma unroll
            for (int j = 0; j < 4; ++j) {
                float l0 = 0.f, l1 = 0.f;
#pragma unroll
                for (int k = 0; k < 4; ++k) {
                    l0 = fmaf(r_tf[j*4+k],      xr[k], l0);
                    l1 = fmaf(r_tf[16 + j*4+k], xr[k], l1);
                }
                s0 += fabsf(l0);
                s1 += fabsf(l1);
            }
        }
    }
    if ((B & 1) && gtid == 0) {
        const float* xs = x + (size_t)(B-1) * 6;
        float xr[4];
#pragma unroll
        for (int j = 0; j < 4; ++j) {
            float a = b_in[j];
#pragma unroll
            for (int k = 0; k < 6; ++k) a = fmaf(W_in[j*6+k], xs[k], a);
            xr[j] = gelu_lut(a, s_lut);
        }
#pragma unroll
        for (int j = 0; j < 4; ++j) {
            float l0 = 0.f, l1 = 0.f;
#pragma unroll
            for (int k = 0; k < 4; ++k) {
                l0 = fmaf(r_tf[j*4+k],      xr[k], l0);
                l1 = fmaf(r_tf[16 + j*4+k], xr[k], l1);
            }
            s0 += fabsf(l0);
            s1 += fabsf(l1);
        }
    }
#pragma unroll
    for (int off = 32; off > 0; off >>= 1) {
        s0 += __shfl_down(s0, off);
        s1 += __shfl_down(s1, off);
    }
    if ((tid & 63) == 0) { s_red[(tid>>6)*2] = s0; s_red[(tid>>6)*2+1] = s1; }
    __syncthreads();
    if (tid == 0) {
        partials[blockIdx.x] = make_float2(s_red[0]+s_red[2]+s_red[4]+s_red[6],
                                           s_red[1]+s_red[3]+s_red[5]+s_red[7]);
    }
}

// ============ kernel 2 (1 block): finalize stats + fold all constants ============
// cst layout: [0]=C0 [1]=C1 [8..23]=tfs0 [24..39]=tfs1 [40..71]=W1e [72..79]=b1e
__global__ __launch_bounds__(256) void k_mid(
    const float2* __restrict__ partials, int nb, int B,
    const float* __restrict__ i_w,  const float* __restrict__ i_b,
    const float* __restrict__ i_tf, const float* __restrict__ i_tc,
    const float* __restrict__ W_ri, const float* __restrict__ b_ri,
    const float* __restrict__ W_ir, const float* __restrict__ b_ir,
    const float* __restrict__ flow_gate, const float* __restrict__ mem,
    const float* __restrict__ W_o1, const float* __restrict__ b_o1,
    const float* __restrict__ r_tf, const float* __restrict__ r_tc,
    float* __restrict__ cst)
{
    const int tid = threadIdx.x;
    __shared__ float s_red[8], s_hc[16], s_cv[4], s_m4[16];

    float t0 = 0.f, t1 = 0.f;
    for (int k = tid; k < nb; k += 256) {
        const float2 pr = partials[k];
        t0 += pr.x; t1 += pr.y;
    }
#pragma unroll
    for (int off = 32; off > 0; off >>= 1) {
        t0 += __shfl_down(t0, off);
        t1 += __shfl_down(t1, off);
    }
    if ((tid & 63) == 0) { s_red[(tid>>6)*2] = t0; s_red[(tid>>6)*2+1] = t1; }
    __syncthreads();
    const float sr = 1.0f / (1.0f + expf(-r_tc[0]));
    if (tid == 0) {
        const float u0 = s_red[0]+s_red[2]+s_red[4]+s_red[6];
        const float u1 = s_red[1]+s_red[3]+s_red[5]+s_red[7];
        const float m0 = u0 / (4.0f * (float)B);
        const float m1 = u1 / (4.0f * (float)B);
        cst[0] = 1.0f / ((m0 + 1e-8f) * sr);   // revolution-domain
        cst[1] = 4.0f / ((m1 + 1e-8f) * sr);
    }

    // constant internal path (weights-only)
    if (tid < 64) {
        const int j = tid & 15;
        float base = i_b[j];
#pragma unroll
        for (int k = 0; k < 16; ++k) base = fmaf(i_w[j*16 + k], mem[k], base);
        float corr = 0.f;
#pragma unroll
        for (int n = 0; n < 3; ++n) {
            float lo = 0.f;
#pragma unroll
            for (int k = 0; k < 16; ++k) lo = fmaf(i_tf[n*256 + j*16 + k], mem[k], lo);
            float a = fabsf(lo);
            a += __shfl_xor(a, 1); a += __shfl_xor(a, 2);
            a += __shfl_xor(a, 4); a += __shfl_xor(a, 8);
            const float mean = a * (1.0f/16.0f);
            const float phase = TWO_PI_F * (float)(n+1) * lo / (mean + 1e-8f);
            corr = fmaf(sinf(phase), lo / (float)(n+1), corr);
        }
        const float sc = 1.0f / (1.0f + expf(-i_tc[0]));
        const float t = fmaf(sc, corr, base);
        float mu = t;
        mu += __shfl_xor(mu, 1); mu += __shfl_xor(mu, 2);
        mu += __shfl_xor(mu, 4); mu += __shfl_xor(mu, 8);
        mu *= (1.0f/16.0f);
        const float d = t - mu;
        float v = d*d;
        v += __shfl_xor(v, 1); v += __shfl_xor(v, 2);
        v += __shfl_xor(v, 4); v += __shfl_xor(v, 8);
        v *= (1.0f/16.0f);
        const float h = gelu_s(d * rsqrtf(v + 1e-5f));
        if (tid < 16) s_hc[j] = h;
    }
    __syncthreads();
    const float g = 1.0f / (1.0f + expf(-flow_gate[0]));
    if (tid < 4) {
        float acc = 0.f;
#pragma unroll
        for (int m = 0; m < 16; ++m)
            acc = fmaf(W_ir[tid*16 + m], fmaf(g, b_ri[m], s_hc[m]), acc);
        s_cv[tid] = g * (acc + b_ir[tid]);
    }
    if (tid < 16) {
        const int l = tid >> 2, j = tid & 3;
        float M = 0.f;
#pragma unroll
        for (int m = 0; m < 16; ++m) M = fmaf(W_ir[l*16 + m], W_ri[m*4 + j], M);
        s_m4[tid] = g * g * M;
        cst[8  + tid] = sr * r_tf[tid];             // tfs0
        cst[24 + tid] = 0.5f * sr * r_tf[16 + tid]; // tfs1
    }
    __syncthreads();
    if (tid < 32) {   // W1e = W_o1 @ (I + M4)
        const int h = tid >> 2, j = tid & 3;
        float we = 0.f;
#pragma unroll
        for (int l = 0; l < 4; ++l)
            we = fmaf(W_o1[h*4 + l], ((l == j) ? 1.0f : 0.0f) + s_m4[l*4 + j], we);
        cst[40 + tid] = we;
    }
    if (tid < 8) {    // b1e = b_o1 + W_o1 @ cvec
        float be = b_o1[tid];
#pragma unroll
        for (int l = 0; l < 4; ++l) be = fmaf(W_o1[tid*4 + l], s_cv[l], be);
        cst[72 + tid] = be;
    }
}

// ============ kernel 3: full per-row pipeline (scalar, LUT gelu) ============
__global__ __launch_bounds__(256, 4) void k_main(
    const float* __restrict__ x,
    const float* __restrict__ W_in, const float* __restrict__ b_in,
    const float* __restrict__ r_w,  const float* __restrict__ r_b,
    const float* __restrict__ W_o2, const float* __restrict__ b_o2,
    const float* __restrict__ cst,
    float* __restrict__ out, int B)
{
    const int tid = threadIdx.x;
    __shared__ float2 s_lut[LUT_N];
    build_lut(s_lut, tid);
    __syncthreads();

    const float C0 = cst[0], C1 = cst[1];

    const int npairs = B >> 1;
    const int TT = gridDim.x * blockDim.x;
    const int gtid = blockIdx.x * blockDim.x + tid;

    for (int p = gtid; p < npairs; p += TT) {
        const float4* xp = (const float4*)(x + (size_t)p * 12);
        float4 q0 = xp[0], q1 = xp[1], q2 = xp[2];
        float xv[2][6] = {{q0.x, q0.y, q0.z, q0.w, q1.x, q1.y},
                          {q1.z, q1.w, q2.x, q2.y, q2.z, q2.w}};
#pragma unroll
        for (int r = 0; r < 2; ++r) {
            float xr[4];
#pragma unroll
            for (int j = 0; j < 4; ++j) {
                float a = b_in[j];
#pragma unroll
                for (int k = 0; k < 6; ++k) a = fmaf(W_in[j*6+k], xv[r][k], a);
                xr[j] = gelu_lut(a, s_lut);
            }
            float t[4];
#pragma unroll
            for (int j = 0; j < 4; ++j) {
                float L0 = 0.f, L1 = 0.f, bse = r_b[j];
#pragma unroll
                for (int k = 0; k < 4; ++k) {
                    L0  = fmaf(cst[8  + j*4+k], xr[k], L0);
                    L1  = fmaf(cst[24 + j*4+k], xr[k], L1);
                    bse = fmaf(r_w[j*4+k],      xr[k], bse);
                }
                t[j] = fmaf(sin_rev(C0*L0), L0, fmaf(sin_rev(C1*L1), L1, bse));
            }
            const float mu = 0.25f * (t[0] + t[1] + t[2] + t[3]);
            float d0 = t[0]-mu, d1 = t[1]-mu, d2 = t[2]-mu, d3 = t[3]-mu;
            float var = fmaf(d0, d0, fmaf(d1, d1, fmaf(d2, d2, d3*d3)));
            const float inv = __builtin_amdgcn_rsqf(fmaf(0.25f, var, 1e-5f));
            float hr[4] = { gelu_lut(d0*inv, s_lut), gelu_lut(d1*inv, s_lut),
                            gelu_lut(d2*inv, s_lut), gelu_lut(d3*inv, s_lut) };

            float hid[8];
#pragma unroll
            for (int h = 0; h < 8; ++h) {
                float a = cst[72 + h];
#pragma unroll
                for (int j = 0; j < 4; ++j) a = fmaf(cst[40 + h*4+j], hr[j], a);
                hid[h] = gelu_lut(a, s_lut);
            }
            float o[4];
#pragma unroll
            for (int oo = 0; oo < 4; ++oo) {
                float a = b_o2[oo];
#pragma unroll
                for (int h = 0; h < 8; ++h) a = fmaf(W_o2[oo*8+h], hid[h], a);
                o[oo] = a;
            }
            float* op = out + (size_t)8*p + (size_t)4*r;
            __builtin_nontemporal_store(o[0], op + 0);
            __builtin_nontemporal_store(o[1], op + 1);
            __builtin_nontemporal_store(o[2], op + 2);
            __builtin_nontemporal_store(o[3], op + 3);
        }
    }

    if ((B & 1) && gtid == 0) {   // tail row
        const float* xs = x + (size_t)(B-1) * 6;
        float xr[4];
#pragma unroll
        for (int j = 0; j < 4; ++j) {
            float a = b_in[j];
#pragma unroll
            for (int k = 0; k < 6; ++k) a = fmaf(W_in[j*6+k], xs[k], a);
            xr[j] = gelu_lut(a, s_lut);
        }
        float t[4];
#pragma unroll
        for (int j = 0; j < 4; ++j) {
            float L0 = 0.f, L1 = 0.f, bse = r_b[j];
#pragma unroll
            for (int k = 0; k < 4; ++k) {
                L0  = fmaf(cst[8  + j*4+k], xr[k], L0);
                L1  = fmaf(cst[24 + j*4+k], xr[k], L1);
                bse = fmaf(r_w[j*4+k],      xr[k], bse);
            }
            t[j] = fmaf(sin_rev(C0*L0), L0, fmaf(sin_rev(C1*L1), L1, bse));
        }
        const float mu = 0.25f * (t[0]+t[1]+t[2]+t[3]);
        float d0=t[0]-mu, d1=t[1]-mu, d2=t[2]-mu, d3=t[3]-mu;
        const float var = 0.25f * (d0*d0 + d1*d1 + d2*d2 + d3*d3);
        const float inv = __builtin_amdgcn_rsqf(var + 1e-5f);
        float hr[4] = { gelu_lut(d0*inv, s_lut), gelu_lut(d1*inv, s_lut),
                        gelu_lut(d2*inv, s_lut), gelu_lut(d3*inv, s_lut) };
        float hid[8];
#pragma unroll
        for (int h = 0; h < 8; ++h) {
            float a = cst[72 + h];
#pragma unroll
            for (int j = 0; j < 4; ++j) a = fmaf(cst[40 + h*4+j], hr[j], a);
            hid[h] = gelu_lut(a, s_lut);
        }
        float o[4];
#pragma unroll
        for (int oo = 0; oo < 4; ++oo) {
            float a = b_o2[oo];
#pragma unroll
            for (int h = 0; h < 8; ++h) a = fmaf(W_o2[oo*8+h], hid[h], a);
            o[oo] = a;
        }
        ((float4*)out)[(size_t)B - 1] = make_float4(o[0], o[1], o[2], o[3]);
    }
}

extern "C" void kernel_launch(void* const* d_in, const int* in_sizes, int n_in,
                              void* d_out, int out_size, void* d_ws, size_t ws_size,
                              hipStream_t stream)
{
    const float* x    = (const float*)d_in[0];
    const float* W_in = (const float*)d_in[1];
    const float* b_in = (const float*)d_in[2];
    const float* r_w  = (const float*)d_in[3];
    const float* r_b  = (const float*)d_in[4];
    const float* r_tf = (const float*)d_in[5];
    const float* r_tc = (const float*)d_in[6];
    const float* i_w  = (const float*)d_in[7];
    const float* i_b  = (const float*)d_in[8];
    const float* i_tf = (const float*)d_in[9];
    const float* i_tc = (const float*)d_in[10];
    const float* W_ri = (const float*)d_in[11];
    const float* b_ri = (const float*)d_in[12];
    const float* W_ir = (const float*)d_in[13];
    const float* b_ir = (const float*)d_in[14];
    const float* fg   = (const float*)d_in[15];
    const float* mem  = (const float*)d_in[16];
    const float* W_o1 = (const float*)d_in[17];
    const float* b_o1 = (const float*)d_in[18];
    const float* W_o2 = (const float*)d_in[19];
    const float* b_o2 = (const float*)d_in[20];
    float* out = (float*)d_out;
    float* ws  = (float*)d_ws;

    const int B = in_sizes[0] / 6;

    // ws layout (floats): [0..127] = cst, [128..] = partials (float2 per k_sum block)
    int NB1 = 1024;
    const long cap = (long)(ws_size / 4) - 128;
    if (cap < 2L * NB1) NB1 = (int)(cap / 2);
    if (NB1 < 1) NB1 = 1;
    float*  cst      = ws;
    float2* partials = (float2*)(ws + 128);

    k_sum<<<NB1, 256, 0, stream>>>(x, W_in, b_in, r_tf, partials, B);

    k_mid<<<1, 256, 0, stream>>>(partials, NB1, B, i_w, i_b, i_tf, i_tc,
                                 W_ri, b_ri, W_ir, b_ir, fg, mem, W_o1, b_o1,
                                 r_tf, r_tc, cst);

    int NB2 = 2048;
    const int npairs = B >> 1;
    if (NB2 * 256 > npairs + 255) NB2 = (npairs + 255) / 256;
    if (NB2 < 1) NB2 = 1;
    k_main<<<NB2, 256, 0, stream>>>(x, W_in, b_in, r_w, r_b, W_o2, b_o2,
                                    cst, out, B);
}

// Round 8
// 42.970 us; speedup vs baseline: 3.3138x; 1.0914x over previous
//
#include <hip/hip_runtime.h>
#include <math.h>

#define TWO_PI_F 6.2831853071795864769f
#define LUT_N    2048
#define LUT_SCALE 170.66666667f   // 2048/12
#define LUT_STEP  0.005859375f    // 12/2048 (exact)

static __device__ __forceinline__ float sin_rev(float x) {   // sin(2*pi*x)
#if __has_builtin(__builtin_amdgcn_sinf)
    return __builtin_amdgcn_sinf(x);
#else
    return __sinf(TWO_PI_F * x);
#endif
}

// accurate branchless CDF: 0.5*(1+erf(x/sqrt2)), A&S 7.1.26 (|err|<=1.5e-7)
static __device__ __forceinline__ float cdf_acc(float v) {
    const float y  = v * 0.70710678118654752f;
    const float ay = fabsf(y);
    const float t  = __builtin_amdgcn_rcpf(fmaf(0.3275911f, ay, 1.0f));
    const float e  = __builtin_amdgcn_exp2f(y * y * -1.4426950408889634f);
    float p = fmaf(1.061405429f, t, -1.453152027f);
    p = fmaf(p, t, 1.421413741f);
    p = fmaf(p, t, -0.284496736f);
    p = fmaf(p, t, 0.254829592f);
    const float erf_abs = 1.0f - p * t * e;
    const float erf_v   = __builtin_copysignf(erf_abs, v);
    return fmaf(0.5f, erf_v, 0.5f);
}
static __device__ __forceinline__ float gelu_s(float v) { return v * cdf_acc(v); }

// LDS-LUT gelu: x * lerp(t_i, t_i+dt_i)
static __device__ __forceinline__ float gelu_lut(float x, const float2* __restrict__ lut) {
    float f = fminf(fmaxf(fmaf(x, LUT_SCALE, 1024.0f), 0.0f), 2047.5f);
    float ff = floorf(f);
    float fr = f - ff;
    float2 e = lut[(int)ff];
    return x * fmaf(fr, e.y, e.x);
}

static __device__ __forceinline__ void build_lut(float2* lut, int tid) {
    for (int i = tid; i < LUT_N; i += 256) {
        float x0 = fmaf((float)i, LUT_STEP, -6.0f);
        float t0 = cdf_acc(x0);
        float t1 = cdf_acc(x0 + LUT_STEP);
        lut[i] = make_float2(t0, t1 - t0);
    }
}

// cst layout: [2]=sr [8..23]=tfs0(sr*tf0) [24..39]=tfs1(0.5*sr*tf1)
//             [40..71]=W1e(8x4) [72..79]=b1e(8)
// ============ kernel 1: batch |lo| sums; block 0 folds weight-only constants ========
__global__ __launch_bounds__(256, 8) void k_sum(
    const float* __restrict__ x,
    const float* __restrict__ W_in, const float* __restrict__ b_in,
    const float* __restrict__ r_tf, const float* __restrict__ r_tc,
    const float* __restrict__ i_w,  const float* __restrict__ i_b,
    const float* __restrict__ i_tf, const float* __restrict__ i_tc,
    const float* __restrict__ W_ri, const float* __restrict__ b_ri,
    const float* __restrict__ W_ir, const float* __restrict__ b_ir,
    const float* __restrict__ flow_gate, const float* __restrict__ mem,
    const float* __restrict__ W_o1, const float* __restrict__ b_o1,
    float2* __restrict__ partials, float* __restrict__ cst, int B)
{
    const int tid = threadIdx.x;
    __shared__ float2 s_lut[LUT_N];
    __shared__ float s_red[8], s_hc[16], s_cv[4], s_m4[16];
    build_lut(s_lut, tid);

    if (blockIdx.x == 0) {
        // constant internal path (weights-only; no batch stats needed)
        if (tid < 64) {
            const int j = tid & 15;
            float base = i_b[j];
#pragma unroll
            for (int k = 0; k < 16; ++k) base = fmaf(i_w[j*16 + k], mem[k], base);
            float corr = 0.f;
#pragma unroll
            for (int n = 0; n < 3; ++n) {
                float lo = 0.f;
#pragma unroll
                for (int k = 0; k < 16; ++k) lo = fmaf(i_tf[n*256 + j*16 + k], mem[k], lo);
                float a = fabsf(lo);
                a += __shfl_xor(a, 1); a += __shfl_xor(a, 2);
                a += __shfl_xor(a, 4); a += __shfl_xor(a, 8);
                const float mean = a * (1.0f/16.0f);
                const float phase = TWO_PI_F * (float)(n+1) * lo / (mean + 1e-8f);
                corr = fmaf(sinf(phase), lo / (float)(n+1), corr);
            }
            const float sc = 1.0f / (1.0f + expf(-i_tc[0]));
            const float t = fmaf(sc, corr, base);
            float mu = t;
            mu += __shfl_xor(mu, 1); mu += __shfl_xor(mu, 2);
            mu += __shfl_xor(mu, 4); mu += __shfl_xor(mu, 8);
            mu *= (1.0f/16.0f);
            const float d = t - mu;
            float v = d*d;
            v += __shfl_xor(v, 1); v += __shfl_xor(v, 2);
            v += __shfl_xor(v, 4); v += __shfl_xor(v, 8);
            v *= (1.0f/16.0f);
            const float h = gelu_s(d * rsqrtf(v + 1e-5f));
            if (tid < 16) s_hc[j] = h;
        }
        __syncthreads();
        const float g  = 1.0f / (1.0f + expf(-flow_gate[0]));
        const float sr = 1.0f / (1.0f + expf(-r_tc[0]));
        if (tid < 4) {
            float acc = 0.f;
#pragma unroll
            for (int m = 0; m < 16; ++m)
                acc = fmaf(W_ir[tid*16 + m], fmaf(g, b_ri[m], s_hc[m]), acc);
            s_cv[tid] = g * (acc + b_ir[tid]);
        }
        if (tid < 16) {
            const int l = tid >> 2, j = tid & 3;
            float M = 0.f;
#pragma unroll
            for (int m = 0; m < 16; ++m) M = fmaf(W_ir[l*16 + m], W_ri[m*4 + j], M);
            s_m4[tid] = g * g * M;
            cst[8  + tid] = sr * r_tf[tid];             // tfs0
            cst[24 + tid] = 0.5f * sr * r_tf[16 + tid]; // tfs1
        }
        if (tid == 0) cst[2] = sr;
        __syncthreads();
        if (tid < 32) {   // W1e = W_o1 @ (I + M4)
            const int h = tid >> 2, j = tid & 3;
            float we = 0.f;
#pragma unroll
            for (int l = 0; l < 4; ++l)
                we = fmaf(W_o1[h*4 + l], ((l == j) ? 1.0f : 0.0f) + s_m4[l*4 + j], we);
            cst[40 + tid] = we;
        }
        if (tid < 8) {    // b1e = b_o1 + W_o1 @ cvec
            float be = b_o1[tid];
#pragma unroll
            for (int l = 0; l < 4; ++l) be = fmaf(W_o1[tid*4 + l], s_cv[l], be);
            cst[72 + tid] = be;
        }
    }
    __syncthreads();   // LUT ready (all blocks)

    const int npairs = B >> 1;
    const int TT = gridDim.x * blockDim.x;
    const int gtid = blockIdx.x * blockDim.x + tid;
    float s0 = 0.f, s1 = 0.f;

    for (int p = gtid; p < npairs; p += TT) {
        const float4* xp = (const float4*)(x + (size_t)p * 12);
        float4 q0 = xp[0], q1 = xp[1], q2 = xp[2];
        float xv[2][6] = {{q0.x, q0.y, q0.z, q0.w, q1.x, q1.y},
                          {q1.z, q1.w, q2.x, q2.y, q2.z, q2.w}};
#pragma unroll
        for (int r = 0; r < 2; ++r) {
            float xr[4];
#pragma unroll
            for (int j = 0; j < 4; ++j) {
                float a = b_in[j];
#pragma unroll
                for (int k = 0; k < 6; ++k) a = fmaf(W_in[j*6+k], xv[r][k], a);
                xr[j] = gelu_lut(a, s_lut);
            }
#pragma unroll
            for (int j = 0; j < 4; ++j) {
                float l0 = 0.f, l1 = 0.f;
#pragma unroll
                for (int k = 0; k < 4; ++k) {
                    l0 = fmaf(r_tf[j*4+k],      xr[k], l0);
                    l1 = fmaf(r_tf[16 + j*4+k], xr[k], l1);
                }
                s0 += fabsf(l0);
                s1 += fabsf(l1);
            }
        }
    }
    if ((B & 1) && gtid == 0) {
        const float* xs = x + (size_t)(B-1) * 6;
        float xr[4];
#pragma unroll
        for (int j = 0; j < 4; ++j) {
            float a = b_in[j];
#pragma unroll
            for (int k = 0; k < 6; ++k) a = fmaf(W_in[j*6+k], xs[k], a);
            xr[j] = gelu_lut(a, s_lut);
        }
#pragma unroll
        for (int j = 0; j < 4; ++j) {
            float l0 = 0.f, l1 = 0.f;
#pragma unroll
            for (int k = 0; k < 4; ++k) {
                l0 = fmaf(r_tf[j*4+k],      xr[k], l0);
                l1 = fmaf(r_tf[16 + j*4+k], xr[k], l1);
            }
            s0 += fabsf(l0);
            s1 += fabsf(l1);
        }
    }
#pragma unroll
    for (int off = 32; off > 0; off >>= 1) {
        s0 += __shfl_down(s0, off);
        s1 += __shfl_down(s1, off);
    }
    if ((tid & 63) == 0) { s_red[(tid>>6)*2] = s0; s_red[(tid>>6)*2+1] = s1; }
    __syncthreads();
    if (tid == 0) {
        partials[blockIdx.x] = make_float2(s_red[0]+s_red[2]+s_red[4]+s_red[6],
                                           s_red[1]+s_red[3]+s_red[5]+s_red[7]);
    }
}

// ============ kernel 2: per-block partial reduce (redundant) + per-row pipeline =====
__global__ __launch_bounds__(256, 6) void k_main(
    const float* __restrict__ x,
    const float* __restrict__ W_in, const float* __restrict__ b_in,
    const float* __restrict__ r_w,  const float* __restrict__ r_b,
    const float* __restrict__ W_o2, const float* __restrict__ b_o2,
    const float2* __restrict__ partials, int nb,
    const float* __restrict__ cst,
    float* __restrict__ out, int B)
{
    const int tid = threadIdx.x;
    __shared__ float2 s_lut[LUT_N];
    __shared__ float s_red[8];
    __shared__ float s_c[2];
    build_lut(s_lut, tid);

    // redundant deterministic reduce of block partials (identical result per block)
    float t0 = 0.f, t1 = 0.f;
    for (int k = tid; k < nb; k += 256) {
        const float2 pr = partials[k];
        t0 += pr.x; t1 += pr.y;
    }
#pragma unroll
    for (int off = 32; off > 0; off >>= 1) {
        t0 += __shfl_down(t0, off);
        t1 += __shfl_down(t1, off);
    }
    if ((tid & 63) == 0) { s_red[(tid>>6)*2] = t0; s_red[(tid>>6)*2+1] = t1; }
    __syncthreads();
    if (tid == 0) {
        const float sr = cst[2];
        const float u0 = s_red[0]+s_red[2]+s_red[4]+s_red[6];
        const float u1 = s_red[1]+s_red[3]+s_red[5]+s_red[7];
        const float m0 = u0 / (4.0f * (float)B);
        const float m1 = u1 / (4.0f * (float)B);
        s_c[0] = 1.0f / ((m0 + 1e-8f) * sr);   // revolution-domain
        s_c[1] = 4.0f / ((m1 + 1e-8f) * sr);
    }
    __syncthreads();
    const float C0 = s_c[0], C1 = s_c[1];

    const int npairs = B >> 1;
    const int TT = gridDim.x * blockDim.x;
    const int gtid = blockIdx.x * blockDim.x + tid;

    for (int p = gtid; p < npairs; p += TT) {
        const float4* xp = (const float4*)(x + (size_t)p * 12);
        float4 q0 = xp[0], q1 = xp[1], q2 = xp[2];
        float xv[2][6] = {{q0.x, q0.y, q0.z, q0.w, q1.x, q1.y},
                          {q1.z, q1.w, q2.x, q2.y, q2.z, q2.w}};
        float o2[2][4];
#pragma unroll
        for (int r = 0; r < 2; ++r) {
            float xr[4];
#pragma unroll
            for (int j = 0; j < 4; ++j) {
                float a = b_in[j];
#pragma unroll
                for (int k = 0; k < 6; ++k) a = fmaf(W_in[j*6+k], xv[r][k], a);
                xr[j] = gelu_lut(a, s_lut);
            }
            float t[4];
#pragma unroll
            for (int j = 0; j < 4; ++j) {
                float L0 = 0.f, L1 = 0.f, bse = r_b[j];
#pragma unroll
                for (int k = 0; k < 4; ++k) {
                    L0  = fmaf(cst[8  + j*4+k], xr[k], L0);
                    L1  = fmaf(cst[24 + j*4+k], xr[k], L1);
                    bse = fmaf(r_w[j*4+k],      xr[k], bse);
                }
                t[j] = fmaf(sin_rev(C0*L0), L0, fmaf(sin_rev(C1*L1), L1, bse));
            }
            const float mu = 0.25f * (t[0] + t[1] + t[2] + t[3]);
            float d0 = t[0]-mu, d1 = t[1]-mu, d2 = t[2]-mu, d3 = t[3]-mu;
            float var = fmaf(d0, d0, fmaf(d1, d1, fmaf(d2, d2, d3*d3)));
            const float inv = __builtin_amdgcn_rsqf(fmaf(0.25f, var, 1e-5f));
            float hr[4] = { gelu_lut(d0*inv, s_lut), gelu_lut(d1*inv, s_lut),
                            gelu_lut(d2*inv, s_lut), gelu_lut(d3*inv, s_lut) };

            float hid[8];
#pragma unroll
            for (int h = 0; h < 8; ++h) {
                float a = cst[72 + h];
#pragma unroll
                for (int j = 0; j < 4; ++j) a = fmaf(cst[40 + h*4+j], hr[j], a);
                hid[h] = gelu_lut(a, s_lut);
            }
#pragma unroll
            for (int oo = 0; oo < 4; ++oo) {
                float a = b_o2[oo];
#pragma unroll
                for (int h = 0; h < 8; ++h) a = fmaf(W_o2[oo*8+h], hid[h], a);
                o2[r][oo] = a;
            }
        }
        typedef float v4f __attribute__((ext_vector_type(4)));
        v4f r0 = (v4f){ o2[0][0], o2[0][1], o2[0][2], o2[0][3] };
        v4f r1 = (v4f){ o2[1][0], o2[1][1], o2[1][2], o2[1][3] };
        __builtin_nontemporal_store(r0, (v4f*)out + (size_t)2*p);
        __builtin_nontemporal_store(r1, (v4f*)out + (size_t)2*p + 1);
    }

    if ((B & 1) && gtid == 0) {   // tail row
        const float* xs = x + (size_t)(B-1) * 6;
        float xr[4];
#pragma unroll
        for (int j = 0; j < 4; ++j) {
            float a = b_in[j];
#pragma unroll
            for (int k = 0; k < 6; ++k) a = fmaf(W_in[j*6+k], xs[k], a);
            xr[j] = gelu_lut(a, s_lut);
        }
        float t[4];
#pragma unroll
        for (int j = 0; j < 4; ++j) {
            float L0 = 0.f, L1 = 0.f, bse = r_b[j];
#pragma unroll
            for (int k = 0; k < 4; ++k) {
                L0  = fmaf(cst[8  + j*4+k], xr[k], L0);
                L1  = fmaf(cst[24 + j*4+k], xr[k], L1);
                bse = fmaf(r_w[j*4+k],      xr[k], bse);
            }
            t[j] = fmaf(sin_rev(C0*L0), L0, fmaf(sin_rev(C1*L1), L1, bse));
        }
        const float mu = 0.25f * (t[0]+t[1]+t[2]+t[3]);
        float d0=t[0]-mu, d1=t[1]-mu, d2=t[2]-mu, d3=t[3]-mu;
        const float var = 0.25f * (d0*d0 + d1*d1 + d2*d2 + d3*d3);
        const float inv = __builtin_amdgcn_rsqf(var + 1e-5f);
        float hr[4] = { gelu_lut(d0*inv, s_lut), gelu_lut(d1*inv, s_lut),
                        gelu_lut(d2*inv, s_lut), gelu_lut(d3*inv, s_lut) };
        float hid[8];
#pragma unroll
        for (int h = 0; h < 8; ++h) {
            float a = cst[72 + h];
#pragma unroll
            for (int j = 0; j < 4; ++j) a = fmaf(cst[40 + h*4+j], hr[j], a);
            hid[h] = gelu_lut(a, s_lut);
        }
        float o[4];
#pragma unroll
        for (int oo = 0; oo < 4; ++oo) {
            float a = b_o2[oo];
#pragma unroll
            for (int h = 0; h < 8; ++h) a = fmaf(W_o2[oo*8+h], hid[h], a);
            o[oo] = a;
        }
        ((float4*)out)[(size_t)B - 1] = make_float4(o[0], o[1], o[2], o[3]);
    }
}

extern "C" void kernel_launch(void* const* d_in, const int* in_sizes, int n_in,
                              void* d_out, int out_size, void* d_ws, size_t ws_size,
                              hipStream_t stream)
{
    const float* x    = (const float*)d_in[0];
    const float* W_in = (const float*)d_in[1];
    const float* b_in = (const float*)d_in[2];
    const float* r_w  = (const float*)d_in[3];
    const float* r_b  = (const float*)d_in[4];
    const float* r_tf = (const float*)d_in[5];
    const float* r_tc = (const float*)d_in[6];
    const float* i_w  = (const float*)d_in[7];
    const float* i_b  = (const float*)d_in[8];
    const float* i_tf = (const float*)d_in[9];
    const float* i_tc = (const float*)d_in[10];
    const float* W_ri = (const float*)d_in[11];
    const float* b_ri = (const float*)d_in[12];
    const float* W_ir = (const float*)d_in[13];
    const float* b_ir = (const float*)d_in[14];
    const float* fg   = (const float*)d_in[15];
    const float* mem  = (const float*)d_in[16];
    const float* W_o1 = (const float*)d_in[17];
    const float* b_o1 = (const float*)d_in[18];
    const float* W_o2 = (const float*)d_in[19];
    const float* b_o2 = (const float*)d_in[20];
    float* out = (float*)d_out;
    float* ws  = (float*)d_ws;

    const int B = in_sizes[0] / 6;
    const int npairs = B >> 1;

    // ws layout (floats): [0..127] = cst, [128..] = partials (float2 per k_sum block)
    int NB1 = 2048;                       // 8 blocks/CU co-resident; npairs % (NB1*256) == 0
    const long cap = (long)(ws_size / 4) - 128;
    if (cap < 2L * NB1) NB1 = (int)(cap / 2);
    if (NB1 < 1) NB1 = 1;
    float*  cst      = ws;
    float2* partials = (float2*)(ws + 128);

    k_sum<<<NB1, 256, 0, stream>>>(x, W_in, b_in, r_tf, r_tc, i_w, i_b, i_tf, i_tc,
                                   W_ri, b_ri, W_ir, b_ir, fg, mem, W_o1, b_o1,
                                   partials, cst, B);

    int NB2 = 1536;                       // 6 blocks/CU co-resident
    if (NB2 * 256 > npairs + 255) NB2 = (npairs + 255) / 256;
    if (NB2 < 1) NB2 = 1;
    k_main<<<NB2, 256, 0, stream>>>(x, W_in, b_in, r_w, r_b, W_o2, b_o2,
                                    partials, NB1, cst, out, B);
}